// Round 2
// 562.786 us; speedup vs baseline: 1.1214x; 1.1214x over previous
//
#include <hip/hip_runtime.h>
#include <stdint.h>

// Gemma2 attention (B=1). Global tensors are FLOAT32; MFMA compute is bf16.
#define S_LEN 2048
#define HDIM  3584
#define NHEAD 16
#define NKVH  8
#define DHEAD 256
#define QD    (NHEAD * DHEAD)   // 4096
#define KD    (NKVH * DHEAD)    // 2048
#define QKVD  (QD + 2 * KD)     // 8192
#define WINDOW 1024
#define MASK_VAL (-1e9f)

typedef __bf16 bf16x8 __attribute__((ext_vector_type(8)));
typedef float  f32x4  __attribute__((ext_vector_type(4)));

__device__ __forceinline__ float bf2f(ushort u) {
    union { uint32_t i; float f; } v; v.i = ((uint32_t)u) << 16; return v.f;
}
__device__ __forceinline__ ushort f2bf(float f) {
    union { float f; uint32_t i; } v; v.f = f;
    uint32_t r = (v.i + 0x7FFF + ((v.i >> 16) & 1)) >> 16;  // RNE
    return (ushort)r;
}
__device__ __forceinline__ void gll16(const ushort* g, ushort* l) {
    __builtin_amdgcn_global_load_lds(
        (const __attribute__((address_space(1))) void*)g,
        (__attribute__((address_space(3))) void*)l, 16, 0, 0);
}

// ---------------------------------------------------------------------------
// Fused f32->bf16 convert for hidden + wq + wk + wv + wo (Tier A).
// ---------------------------------------------------------------------------
#define N_H8  (S_LEN * HDIM / 8)       // 917504
#define N_WQ8 (QD * HDIM / 8)          // 1835008
#define N_WK8 (KD * HDIM / 8)          // 917504
#define N_WO8 (HDIM * QD / 8)          // 1835008
#define N_CVT (N_H8 + N_WQ8 + 2 * N_WK8 + N_WO8)

__global__ __launch_bounds__(256) void cvt5_kernel(
    const float* __restrict__ hid, const float* __restrict__ wq,
    const float* __restrict__ wk,  const float* __restrict__ wv,
    const float* __restrict__ wo,
    ushort* __restrict__ hb, ushort* __restrict__ wb, ushort* __restrict__ ob)
{
    int j = blockIdx.x * blockDim.x + threadIdx.x;
    const float* s; ushort* d;
    if (j < N_H8)                { s = hid; d = hb; }
    else if ((j -= N_H8) < N_WQ8)  { s = wq; d = wb; }
    else if ((j -= N_WQ8) < N_WK8) { s = wk; d = wb + (size_t)QD * HDIM; }
    else if ((j -= N_WK8) < N_WK8) { s = wv; d = wb + (size_t)(QD + KD) * HDIM; }
    else                         { j -= N_WK8; s = wo; d = ob; }
    float4 a = ((const float4*)s)[(size_t)j * 2];
    float4 b = ((const float4*)s)[(size_t)j * 2 + 1];
    ushort tmp[8];
    tmp[0] = f2bf(a.x); tmp[1] = f2bf(a.y); tmp[2] = f2bf(a.z); tmp[3] = f2bf(a.w);
    tmp[4] = f2bf(b.x); tmp[5] = f2bf(b.y); tmp[6] = f2bf(b.z); tmp[7] = f2bf(b.w);
    ((uint4*)d)[j] = *(uint4*)tmp;
}

// single-tensor convert (Tier B)
__global__ __launch_bounds__(256) void cvt_kernel(const float* __restrict__ src,
                                                  ushort* __restrict__ dst, int n8)
{
    int i = blockIdx.x * blockDim.x + threadIdx.x;
    if (i >= n8) return;
    float4 a = ((const float4*)src)[i * 2];
    float4 b = ((const float4*)src)[i * 2 + 1];
    ushort tmp[8];
    tmp[0] = f2bf(a.x); tmp[1] = f2bf(a.y); tmp[2] = f2bf(a.z); tmp[3] = f2bf(a.w);
    tmp[4] = f2bf(b.x); tmp[5] = f2bf(b.y); tmp[6] = f2bf(b.z); tmp[7] = f2bf(b.w);
    ((uint4*)dst)[i] = *(uint4*)tmp;
}

// ---------------------------------------------------------------------------
// f32 tile staging with convert, bank-swizzled (legacy 128x32 layout).
// ---------------------------------------------------------------------------
__device__ __forceinline__ void stage_f32(ushort* __restrict__ dst,
                                          const float* __restrict__ src,
                                          int r0, int K, int kt, int t)
{
#pragma unroll
    for (int i = 0; i < 4; i++) {
        int g = t + i * 256;
        int row = g >> 3, c = g & 7;
        float4 f = *(const float4*)(src + (size_t)(r0 + row) * K + kt + c * 4);
        ushort4 u;
        u.x = f2bf(f.x); u.y = f2bf(f.y); u.z = f2bf(f.z); u.w = f2bf(f.w);
        int cl = (c >> 1) ^ ((row >> 1) & 3);
        *(ushort4*)(dst + row * 32 + cl * 8 + (c & 1) * 4) = u;
    }
}

// ===========================================================================
// 256x256 8-phase GEMM (T2+T3+T4+T5):  C[M,N] = A[M,K] * B[N,K]^T, bf16 in.
// 512 threads = 8 waves (2M x 4N), BK=64, 128 KiB LDS double buffer.
// LDS tile [256][64] bf16, 16B chunk sc holds logical chunk sc^(row&7)
// (bank-conflict-free ds_read_b128; applied via pre-swizzled gll source).
// Phase = one C-quadrant (qm half of wave's 8 mi, qn half of 4 ni) x K=64:
// 16 MFMA, 8-12 ds_read_b128, 1 half-tile (16KB) staged, counted vmcnt(6)
// at even-phase tails only (never 0 in main loop).
// All waitcnt asm carries "memory" clobber: raw s_barrier has no fence
// semantics, so the clobbers pin plain-C++ ds_reads / stage issues in place.
// ===========================================================================
#define VM6   asm volatile("s_waitcnt vmcnt(6)" ::: "memory")
#define VM0   asm volatile("s_waitcnt vmcnt(0)" ::: "memory")
#define LGKM0 asm volatile("s_waitcnt lgkmcnt(0)" ::: "memory")
#define MFEN  asm volatile("" ::: "memory")

#define PHASE(BUF, QM, QN, LA, LB, STAGE, TWAIT) do {                          \
    if (LA) {                                                                  \
      _Pragma("unroll") for (int i_ = 0; i_ < 4; i_++) {                       \
        int R_ = wm + (QM) * 64 + i_ * 16 + l15;                               \
        afr[i_][0] = *(const bf16x8*)(&As[BUF][R_ * 64 + ((quad ^ (R_ & 7)) * 8)]);       \
        afr[i_][1] = *(const bf16x8*)(&As[BUF][R_ * 64 + (((4 + quad) ^ (R_ & 7)) * 8)]); \
      }                                                                        \
    }                                                                          \
    if (LB) {                                                                  \
      _Pragma("unroll") for (int n_ = 0; n_ < 2; n_++) {                       \
        int R_ = wn + (QN) * 32 + n_ * 16 + l15;                               \
        bfr[n_][0] = *(const bf16x8*)(&Bs[BUF][R_ * 64 + ((quad ^ (R_ & 7)) * 8)]);       \
        bfr[n_][1] = *(const bf16x8*)(&Bs[BUF][R_ * 64 + (((4 + quad) ^ (R_ & 7)) * 8)]); \
      }                                                                        \
    }                                                                          \
    STAGE;                                                                     \
    MFEN;                                                                      \
    __builtin_amdgcn_s_barrier();                                              \
    LGKM0;                                                                     \
    __builtin_amdgcn_s_setprio(1);                                             \
    _Pragma("unroll") for (int i_ = 0; i_ < 4; i_++)                           \
      _Pragma("unroll") for (int n_ = 0; n_ < 2; n_++) {                       \
        acc[(QM) * 4 + i_][(QN) * 2 + n_] = __builtin_amdgcn_mfma_f32_16x16x32_bf16(  \
            afr[i_][0], bfr[n_][0], acc[(QM) * 4 + i_][(QN) * 2 + n_], 0, 0, 0);      \
        acc[(QM) * 4 + i_][(QN) * 2 + n_] = __builtin_amdgcn_mfma_f32_16x16x32_bf16(  \
            afr[i_][1], bfr[n_][1], acc[(QM) * 4 + i_][(QN) * 2 + n_], 0, 0, 0);      \
      }                                                                        \
    __builtin_amdgcn_s_setprio(0);                                             \
    TWAIT;                                                                     \
    __builtin_amdgcn_s_barrier();                                              \
    MFEN;                                                                      \
  } while (0)

template <typename TC>
__global__ __launch_bounds__(512, 2) void gemm256(const ushort* __restrict__ A,
                                                  const ushort* __restrict__ B,
                                                  TC* __restrict__ C,
                                                  int M, int N, int K)
{
    __shared__ __align__(16) ushort As[2][256 * 64];
    __shared__ __align__(16) ushort Bs[2][256 * 64];

    const int t    = threadIdx.x;
    const int lane = t & 63;
    const int w    = t >> 6;          // 0..7
    const int l15  = lane & 15;
    const int quad = lane >> 4;
    const int m0   = blockIdx.y * 256;
    const int n0   = blockIdx.x * 256;
    const int wm   = (w >> 2) * 128;  // 0 / 128
    const int wn   = (w & 3) * 64;    // 0 / 64 / 128 / 192
    const int lr8  = lane >> 3;       // row within 8-row wave chunk
    const int sc   = lane & 7;        // stored 16B chunk

    f32x4 acc[8][4] = {};
    bf16x8 afr[4][2], bfr[2][2];

    // half-tile staging: A-q<qm> = rows {qm*64..+63} u {128+qm*64..+63};
    //                    B-q<qn> = rows {s*64+qn*32..+31 : s=0..3}. 2 gll/thread.
    auto stageA = [&](int buf, int qm, int tile) {
#pragma unroll
        for (int i = 0; i < 2; i++) {
            int cb  = (i * 8 + w) * 8;                         // base local row
            int lr  = cb + lr8;
            int row = qm * 64 + (lr & 63) + ((lr >> 6) << 7);  // tile/LDS row
            int rb  = qm * 64 + (cb & 63) + ((cb >> 6) << 7);  // wave-uniform base row
            gll16(A + (size_t)(m0 + row) * K + tile * 64 + ((sc ^ lr8) * 8),
                  &As[buf][rb * 64]);
        }
    };
    auto stageB = [&](int buf, int qn, int tile) {
#pragma unroll
        for (int i = 0; i < 2; i++) {
            int cb  = (i * 8 + w) * 8;
            int lr  = cb + lr8;
            int row = ((lr >> 5) << 6) + qn * 32 + (lr & 31);
            int rb  = ((cb >> 5) << 6) + qn * 32 + (cb & 31);
            gll16(B + (size_t)(n0 + row) * K + tile * 64 + ((sc ^ lr8) * 8),
                  &Bs[buf][rb * 64]);
        }
    };

    // Prologue: stage t0 fully + t1.{B-q0, A-q1}, in steady-state slot order.
    stageB(0, 0, 0);
    stageA(0, 1, 0);
    stageA(0, 0, 0);
    stageB(0, 1, 0);
    stageB(1, 0, 1);
    stageA(1, 1, 1);
    VM6;                               // oldest 3 half-tiles (t0.Bq0,Aq1,Aq0) landed
    __builtin_amdgcn_s_barrier();
    MFEN;

    const int NJ = K >> 7;             // 2 K-tiles (BK=64 each) per iteration
    for (int j = 0; j < NJ; ++j) {
        const int T = 2 * j;
        const bool tl = (j == NJ - 1);
        // tile T from buf0
        PHASE(0, 0, 0, 1, 1, stageA(1, 0, T + 1), MFEN);
        PHASE(0, 1, 0, 1, 0, stageB(1, 1, T + 1), if (tl) { VM0; } else { VM6; });
        PHASE(0, 1, 1, 0, 1, if (!tl) { stageB(0, 0, T + 2); }, MFEN);
        PHASE(0, 0, 1, 1, 0, if (!tl) { stageA(0, 1, T + 2); }, if (!tl) { VM6; } else { MFEN; });
        // tile T+1 from buf1
        PHASE(1, 0, 0, 1, 1, if (!tl) { stageA(0, 0, T + 2); }, MFEN);
        PHASE(1, 1, 0, 1, 0, if (!tl) { stageB(0, 1, T + 2); }, if (!tl) { VM6; } else { MFEN; });
        PHASE(1, 1, 1, 0, 1, if (!tl) { stageB(1, 0, T + 3); }, MFEN);
        PHASE(1, 0, 1, 1, 0, if (!tl) { stageA(1, 1, T + 3); }, if (!tl) { VM6; } else { MFEN; });
    }

    // Epilogue C-write (same lane mapping as legacy kernel; K-order identical).
#pragma unroll
    for (int qm = 0; qm < 2; qm++)
#pragma unroll
      for (int i = 0; i < 4; i++)
#pragma unroll
        for (int qn = 0; qn < 2; qn++)
#pragma unroll
          for (int n = 0; n < 2; n++)
#pragma unroll
            for (int r = 0; r < 4; r++) {
                int row = m0 + wm + qm * 64 + i * 16 + quad * 4 + r;
                int col = n0 + wn + qn * 32 + n * 16 + l15;
                float val = acc[qm * 4 + i][qn * 2 + n][r];
                if constexpr (sizeof(TC) == 4) C[(size_t)row * N + col] = val;
                else                           C[(size_t)row * N + col] = f2bf(val);
            }
}

// ---------------------------------------------------------------------------
// Legacy 128x128 GEMM (Tier B QKV: f32 A staging path).
// ---------------------------------------------------------------------------
template <typename TA, typename TC>
__global__ __launch_bounds__(256) void gemm_async(const TA* __restrict__ A,
                                                  const ushort* __restrict__ B,
                                                  TC* __restrict__ C,
                                                  int M, int N, int K)
{
    __shared__ __align__(16) ushort As[128 * 32];
    __shared__ __align__(16) ushort Bs[128 * 32];

    const int t    = threadIdx.x;
    const int lane = t & 63;
    const int w    = t >> 6;
    const int l15  = lane & 15;
    const int quad = lane >> 4;
    const int m0   = blockIdx.y * 128;
    const int n0   = blockIdx.x * 128;
    const int wm   = (w >> 1) * 64;
    const int wn   = (w & 1) * 64;
    const int srow = lane >> 2;
    const int scol = ((lane & 3) ^ ((srow >> 1) & 3)) * 8;
    const int sw   = (l15 >> 1) & 3;

    f32x4 acc[4][4] = {};

    for (int kt = 0; kt < K; kt += 32) {
        __syncthreads();
#pragma unroll
        for (int j = 0; j < 2; j++) {
            const int rb = w * 32 + j * 16;
            if constexpr (sizeof(TA) == 2) {
                gll16((const ushort*)A + (size_t)(m0 + rb + srow) * K + kt + scol,
                      As + rb * 32);
            }
            gll16(B + (size_t)(n0 + rb + srow) * K + kt + scol, Bs + rb * 32);
        }
        if constexpr (sizeof(TA) == 4)
            stage_f32(As, (const float*)A, m0, K, kt, t);
        __syncthreads();

        bf16x8 a[4], b[4];
#pragma unroll
        for (int mi = 0; mi < 4; mi++)
            a[mi] = *(const bf16x8*)(As + (wm + mi * 16 + l15) * 32 + (quad ^ sw) * 8);
#pragma unroll
        for (int ni = 0; ni < 4; ni++)
            b[ni] = *(const bf16x8*)(Bs + (wn + ni * 16 + l15) * 32 + (quad ^ sw) * 8);
#pragma unroll
        for (int mi = 0; mi < 4; mi++)
#pragma unroll
            for (int ni = 0; ni < 4; ni++)
                acc[mi][ni] = __builtin_amdgcn_mfma_f32_16x16x32_bf16(
                    a[mi], b[ni], acc[mi][ni], 0, 0, 0);
    }

#pragma unroll
    for (int mi = 0; mi < 4; mi++)
#pragma unroll
        for (int ni = 0; ni < 4; ni++)
#pragma unroll
            for (int r = 0; r < 4; r++) {
                int row = m0 + wm + mi * 16 + quad * 4 + r;
                int col = n0 + wn + ni * 16 + l15;
                float val = acc[mi][ni][r];
                if constexpr (sizeof(TC) == 4) C[(size_t)row * N + col] = val;
                else                           C[(size_t)row * N + col] = f2bf(val);
            }
}

// ---------------------------------------------------------------------------
// Slow-fallback GEMMs (Tier C), swizzle-consistent.
// ---------------------------------------------------------------------------
__global__ __launch_bounds__(256) void gemm_sync(const float* __restrict__ A,
                                                 const float* __restrict__ B,
                                                 ushort* __restrict__ C,
                                                 int M, int N, int K)
{
    __shared__ __align__(16) ushort As[128 * 32];
    __shared__ __align__(16) ushort Bs[128 * 32];
    const int t = threadIdx.x, lane = t & 63, w = t >> 6;
    const int l15 = lane & 15, quad = lane >> 4;
    const int sw = (l15 >> 1) & 3;
    const int m0 = blockIdx.y * 128, n0 = blockIdx.x * 128;
    const int wm = (w >> 1) * 64, wn = (w & 1) * 64;
    f32x4 acc[4][4] = {};
    for (int kt = 0; kt < K; kt += 32) {
        __syncthreads();
        stage_f32(As, A, m0, K, kt, t);
        stage_f32(Bs, B, n0, K, kt, t);
        __syncthreads();
        bf16x8 a[4], b[4];
#pragma unroll
        for (int mi = 0; mi < 4; mi++)
            a[mi] = *(const bf16x8*)(As + (wm + mi * 16 + l15) * 32 + (quad ^ sw) * 8);
#pragma unroll
        for (int ni = 0; ni < 4; ni++)
            b[ni] = *(const bf16x8*)(Bs + (wn + ni * 16 + l15) * 32 + (quad ^ sw) * 8);
#pragma unroll
        for (int mi = 0; mi < 4; mi++)
#pragma unroll
            for (int ni = 0; ni < 4; ni++)
                acc[mi][ni] = __builtin_amdgcn_mfma_f32_16x16x32_bf16(
                    a[mi], b[ni], acc[mi][ni], 0, 0, 0);
    }
#pragma unroll
    for (int mi = 0; mi < 4; mi++)
#pragma unroll
        for (int ni = 0; ni < 4; ni++)
#pragma unroll
            for (int r = 0; r < 4; r++)
                C[(size_t)(m0 + wm + mi * 16 + quad * 4 + r) * N +
                  n0 + wn + ni * 16 + l15] = f2bf(acc[mi][ni][r]);
}

__global__ __launch_bounds__(256) void gemm_sync_hf(const ushort* __restrict__ A,
                                                    const float* __restrict__ B,
                                                    float* __restrict__ C,
                                                    int M, int N, int K)
{
    __shared__ __align__(16) ushort As[128 * 32];
    __shared__ __align__(16) ushort Bs[128 * 32];
    const int t = threadIdx.x, lane = t & 63, w = t >> 6;
    const int l15 = lane & 15, quad = lane >> 4;
    const int sw = (l15 >> 1) & 3;
    const int m0 = blockIdx.y * 128, n0 = blockIdx.x * 128;
    const int wm = (w >> 1) * 64, wn = (w & 1) * 64;
    f32x4 acc[4][4] = {};
    for (int kt = 0; kt < K; kt += 32) {
        __syncthreads();
#pragma unroll
        for (int i = 0; i < 2; i++) {
            int g = t + i * 256;
            int row = g >> 2, c = g & 3;
            int cl = c ^ ((row >> 1) & 3);
            *(uint4*)(As + row * 32 + cl * 8) =
                *(const uint4*)(A + (size_t)(m0 + row) * K + kt + c * 8);
        }
        stage_f32(Bs, B, n0, K, kt, t);
        __syncthreads();
        bf16x8 a[4], b[4];
#pragma unroll
        for (int mi = 0; mi < 4; mi++)
            a[mi] = *(const bf16x8*)(As + (wm + mi * 16 + l15) * 32 + (quad ^ sw) * 8);
#pragma unroll
        for (int ni = 0; ni < 4; ni++)
            b[ni] = *(const bf16x8*)(Bs + (wn + ni * 16 + l15) * 32 + (quad ^ sw) * 8);
#pragma unroll
        for (int mi = 0; mi < 4; mi++)
#pragma unroll
            for (int ni = 0; ni < 4; ni++)
                acc[mi][ni] = __builtin_amdgcn_mfma_f32_16x16x32_bf16(
                    a[mi], b[ni], acc[mi][ni], 0, 0, 0);
    }
#pragma unroll
    for (int mi = 0; mi < 4; mi++)
#pragma unroll
        for (int ni = 0; ni < 4; ni++)
#pragma unroll
            for (int r = 0; r < 4; r++)
                C[(size_t)(m0 + wm + mi * 16 + quad * 4 + r) * N +
                  n0 + wn + ni * 16 + l15] = acc[mi][ni][r];
}

// ---------------------------------------------------------------------------
// RoPE in-place on rows of stride `stride`, nh heads at column h*256.
// ---------------------------------------------------------------------------
__global__ void rope_kernel(ushort* __restrict__ x, int stride,
                            const float* __restrict__ cosb,
                            const float* __restrict__ sinb, int nh)
{
    int idx  = blockIdx.x * blockDim.x + threadIdx.x;
    int d    = idx & 127;
    int rest = idx >> 7;
    int h    = rest & (nh - 1);
    int s    = rest / nh;
    size_t base = (size_t)s * stride + h * DHEAD;
    float c  = cosb[s * DHEAD + d];
    float sn = sinb[s * DHEAD + d];
    float x1 = bf2f(x[base + d]);
    float x2 = bf2f(x[base + d + 128]);
    x[base + d]       = f2bf(x1 * c - x2 * sn);
    x[base + d + 128] = f2bf(x2 * c + x1 * sn);
}

// ---------------------------------------------------------------------------
// Transpose V rows (stride) -> Vt [KD][S_LEN], 64x64 tiles.
// ---------------------------------------------------------------------------
__global__ __launch_bounds__(256) void vtrans_kernel(const ushort* __restrict__ v,
                                                     int stride,
                                                     ushort* __restrict__ vt)
{
    __shared__ __align__(16) ushort tile[64][72];
    int s0 = blockIdx.x * 64, c0 = blockIdx.y * 64;
    int t  = threadIdx.x;
#pragma unroll
    for (int i = 0; i < 2; i++) {
        int cI = t + i * 256;
        int row = cI >> 3, c8 = cI & 7;
        *(uint4*)&tile[row][c8 * 8] =
            *(const uint4*)(v + (size_t)(s0 + row) * stride + c0 + c8 * 8);
    }
    __syncthreads();
#pragma unroll
    for (int i = 0; i < 2; i++) {
        int cI = t + i * 256;
        int crow = cI >> 3, s8 = cI & 7;
        ushort tmp[8];
#pragma unroll
        for (int j = 0; j < 8; j++) tmp[j] = tile[s8 * 8 + j][crow];
        *(uint4*)(vt + (size_t)(c0 + crow) * S_LEN + s0 + s8 * 8) = *(uint4*)tmp;
    }
}

// ---------------------------------------------------------------------------
// Flash attention, block = 64 q-rows x 1 head, 4 waves (16 rows each).
// ---------------------------------------------------------------------------
template <typename TO>
__global__ __launch_bounds__(256) void attn_kernel(const ushort* __restrict__ qr, int qstride,
                                                   const ushort* __restrict__ kr, int kstride,
                                                   const ushort* __restrict__ vt,
                                                   TO* __restrict__ out)
{
    __shared__ __align__(16) ushort Ks[64 * 256];   // [key][d] 32KB
    __shared__ __align__(16) ushort Vs[256 * 64];   // [d][key] 32KB
    __shared__ __align__(16) ushort Ps[4][16 * 68]; // padded, 8.5KB

    const int t    = threadIdx.x;
    const int lane = t & 63;
    const int w    = t >> 6;
    const int l15  = lane & 15;
    const int quad = lane >> 4;
    const int q0B  = blockIdx.x * 64;
    const int q0   = q0B + w * 16;
    const int h    = blockIdx.y;
    const int kvh  = h >> 1;  // GROUPS = 2

    bf16x8 aQ[8];
    const ushort* qrow = qr + (size_t)(q0 + l15) * qstride + h * DHEAD;
#pragma unroll
    for (int kk = 0; kk < 8; kk++)
        aQ[kk] = *(const bf16x8*)(qrow + kk * 32 + quad * 8);

    f32x4 oacc[16] = {};
    float m_i[4], l_i[4];
#pragma unroll
    for (int r = 0; r < 4; r++) { m_i[r] = -1e30f; l_i[r] = 0.f; }

    int km = q0B - (WINDOW - 1);
    if (km < 0) km = 0;
    km &= ~63;

    for (int kb = km; kb < q0B + 64; kb += 64) {
        __syncthreads();
#pragma unroll
        for (int i = 0; i < 8; i++) {
            int base = i * 256 + w * 64;
            int idx  = base + lane;
            int row = idx >> 5, c = idx & 31;
            int cs = c ^ (row & 7);
            gll16(kr + (size_t)(kb + row) * kstride + kvh * DHEAD + cs * 8,
                  Ks + base * 8);
        }
#pragma unroll
        for (int i = 0; i < 8; i++) {
            int base = i * 256 + w * 64;
            int idx  = base + lane;
            int row = idx >> 3, c = idx & 7;
            int cs = c ^ (row & 7);
            gll16(vt + (size_t)(kvh * DHEAD + row) * S_LEN + kb + cs * 8,
                  Vs + base * 8);
        }
        __syncthreads();

        // ---- QK^T: S[16q][64k] ----
        f32x4 sc[4] = {};
#pragma unroll
        for (int ni = 0; ni < 4; ni++) {
            int row = ni * 16 + l15;
#pragma unroll
            for (int kk = 0; kk < 8; kk++) {
                int cp = (kk * 4 + quad) ^ (row & 7);
                bf16x8 bk = *(const bf16x8*)(Ks + row * 256 + cp * 8);
                sc[ni] = __builtin_amdgcn_mfma_f32_16x16x32_bf16(aQ[kk], bk, sc[ni], 0, 0, 0);
            }
        }

        // ---- softcap + mask + online softmax ----
        const bool interior = (kb + 63 <= q0) && (q0 + 15 - kb < WINDOW);
        float p[4][4];
        float mt[4] = { -1e30f, -1e30f, -1e30f, -1e30f };
        if (interior) {
#pragma unroll
            for (int ni = 0; ni < 4; ni++)
#pragma unroll
                for (int r = 0; r < 4; r++) {
                    float e = __expf(sc[ni][r] * 0.0025f);
                    float x = 50.f * (e - 1.f) * __builtin_amdgcn_rcpf(e + 1.f);
                    p[ni][r] = x;
                    mt[r] = fmaxf(mt[r], x);
                }
        } else {
#pragma unroll
            for (int ni = 0; ni < 4; ni++)
#pragma unroll
                for (int r = 0; r < 4; r++) {
                    int qi = q0 + quad * 4 + r;
                    int ki = kb + ni * 16 + l15;
                    float e = __expf(sc[ni][r] * 0.0025f);
                    float x = 50.f * (e - 1.f) * __builtin_amdgcn_rcpf(e + 1.f);
                    bool ok = (ki <= qi) && (qi - ki < WINDOW);
                    x = ok ? x : MASK_VAL;
                    p[ni][r] = x;
                    mt[r] = fmaxf(mt[r], x);
                }
        }
#pragma unroll
        for (int r = 0; r < 4; r++)
#pragma unroll
            for (int off = 1; off < 16; off <<= 1)
                mt[r] = fmaxf(mt[r], __shfl_xor(mt[r], off));

        float alpha[4], rs[4];
#pragma unroll
        for (int r = 0; r < 4; r++) {
            float mn = fmaxf(m_i[r], mt[r]);
            alpha[r] = __expf(m_i[r] - mn);
            m_i[r] = mn;
            rs[r] = 0.f;
        }
#pragma unroll
        for (int ni = 0; ni < 4; ni++)
#pragma unroll
            for (int r = 0; r < 4; r++) {
                float pe = __expf(p[ni][r] - m_i[r]);
                rs[r] += pe;
                Ps[w][(quad * 4 + r) * 68 + ni * 16 + l15] = f2bf(pe);
            }
#pragma unroll
        for (int r = 0; r < 4; r++) {
#pragma unroll
            for (int off = 1; off < 16; off <<= 1)
                rs[r] += __shfl_xor(rs[r], off);
            l_i[r] = l_i[r] * alpha[r] + rs[r];
        }
#pragma unroll
        for (int nd = 0; nd < 16; nd++)
#pragma unroll
            for (int r = 0; r < 4; r++)
                oacc[nd][r] *= alpha[r];

        __asm__ volatile("s_waitcnt lgkmcnt(0)" ::: "memory");

        // ---- PV ----
        bf16x8 aP[2];
#pragma unroll
        for (int kk = 0; kk < 2; kk++)
            aP[kk] = *(const bf16x8*)(&Ps[w][l15 * 68 + kk * 32 + quad * 8]);
#pragma unroll
        for (int nd = 0; nd < 16; nd++) {
            int row = nd * 16 + l15;
#pragma unroll
            for (int kk = 0; kk < 2; kk++) {
                int cp = (kk * 4 + quad) ^ (row & 7);
                bf16x8 bv = *(const bf16x8*)(Vs + row * 64 + cp * 8);
                oacc[nd] = __builtin_amdgcn_mfma_f32_16x16x32_bf16(aP[kk], bv, oacc[nd], 0, 0, 0);
            }
        }
    }

#pragma unroll
    for (int r = 0; r < 4; r++) {
        float invl = __builtin_amdgcn_rcpf(l_i[r]);
#pragma unroll
        for (int nd = 0; nd < 16; nd++) {
            int qi = q0 + quad * 4 + r;
            int d  = nd * 16 + l15;
            float val = oacc[nd][r] * invl;
            if constexpr (sizeof(TO) == 4) out[(size_t)qi * QD + h * DHEAD + d] = val;
            else                           out[(size_t)qi * QD + h * DHEAD + d] = f2bf(val);
        }
    }
}

// ---------------------------------------------------------------------------
extern "C" void kernel_launch(void* const* d_in, const int* in_sizes, int n_in,
                              void* d_out, int out_size, void* d_ws, size_t ws_size,
                              hipStream_t stream)
{
    const float* hidden = (const float*)d_in[0];
    const float* cosb   = (const float*)d_in[1];
    const float* sinb   = (const float*)d_in[2];
    const float* wq     = (const float*)d_in[3];
    const float* wk     = (const float*)d_in[4];
    const float* wv     = (const float*)d_in[5];
    const float* wo     = (const float*)d_in[6];
    float* outp = (float*)d_out;

    const size_t nH   = (size_t)S_LEN * HDIM;
    const size_t nWQ  = (size_t)QD * HDIM;
    const size_t nWK  = (size_t)KD * HDIM;
    const size_t nWB  = (size_t)QKVD * HDIM;
    const size_t nWO  = (size_t)HDIM * QD;
    const size_t nQKV = (size_t)S_LEN * QKVD;
    const size_t nAT  = (size_t)S_LEN * QD;
    const size_t nVT  = (size_t)S_LEN * KD;

    dim3 blk(256);
    dim3 blk512(512);
    const size_t needA = (nWB + nQKV + nH + nWO) * 2;
    const size_t needB = (nWB + nQKV) * 2;

    if (ws_size >= needA) {
        ushort* wb  = (ushort*)d_ws;
        ushort* qkv = wb + nWB;
        ushort* hb  = qkv + nQKV;
        ushort* ob  = hb + nH;
        ushort* at  = wb;                      // alias (wb dead after QKV GEMM)
        ushort* vtb = wb + nAT;

        cvt5_kernel<<<(N_CVT + 255) / 256, blk, 0, stream>>>(hidden, wq, wk, wv, wo, hb, wb, ob);
        gemm256<ushort><<<dim3(QKVD / 256, S_LEN / 256), blk512, 0, stream>>>(
            hb, wb, qkv, S_LEN, QKVD, HDIM);
        rope_kernel<<<(S_LEN * NHEAD * 128) / 256, blk, 0, stream>>>(qkv, QKVD, cosb, sinb, NHEAD);
        rope_kernel<<<(S_LEN * NKVH * 128) / 256, blk, 0, stream>>>(qkv + QD, QKVD, cosb, sinb, NKVH);
        vtrans_kernel<<<dim3(S_LEN / 64, KD / 64), blk, 0, stream>>>(qkv + QD + KD, QKVD, vtb);
        attn_kernel<ushort><<<dim3(S_LEN / 64, NHEAD), blk, 0, stream>>>(
            qkv, QKVD, qkv + QD, QKVD, vtb, at);
        gemm256<float><<<dim3(HDIM / 256, S_LEN / 256), blk512, 0, stream>>>(
            at, ob, outp, S_LEN, HDIM, QD);
    } else if (ws_size >= needB) {
        ushort* wb  = (ushort*)d_ws;
        ushort* qkv = wb + nWB;
        ushort* at  = wb;
        ushort* vtb = wb + nAT;
        ushort* ob  = wb + nAT + nVT;

        cvt_kernel<<<(int)(nWQ / 8 / 256), blk, 0, stream>>>(wq, wb, (int)(nWQ / 8));
        cvt_kernel<<<(int)(nWK / 8 / 256), blk, 0, stream>>>(wk, wb + nWQ, (int)(nWK / 8));
        cvt_kernel<<<(int)(nWK / 8 / 256), blk, 0, stream>>>(wv, wb + nWQ + nWK, (int)(nWK / 8));
        gemm_async<float, ushort><<<dim3(QKVD / 128, S_LEN / 128), blk, 0, stream>>>(
            hidden, wb, qkv, S_LEN, QKVD, HDIM);
        cvt_kernel<<<(int)(nWO / 8 / 256), blk, 0, stream>>>(wo, ob, (int)(nWO / 8));
        rope_kernel<<<(S_LEN * NHEAD * 128) / 256, blk, 0, stream>>>(qkv, QKVD, cosb, sinb, NHEAD);
        rope_kernel<<<(S_LEN * NKVH * 128) / 256, blk, 0, stream>>>(qkv + QD, QKVD, cosb, sinb, NKVH);
        vtrans_kernel<<<dim3(S_LEN / 64, KD / 64), blk, 0, stream>>>(qkv + QD + KD, QKVD, vtb);
        attn_kernel<ushort><<<dim3(S_LEN / 64, NHEAD), blk, 0, stream>>>(
            qkv, QKVD, qkv + QD, QKVD, vtb, at);
        gemm256<float><<<dim3(HDIM / 256, S_LEN / 256), blk512, 0, stream>>>(
            at, ob, outp, S_LEN, HDIM, QD);
    } else {
        ushort* q   = (ushort*)d_ws;
        ushort* k   = q + nAT;
        ushort* v   = k + nVT;
        ushort* vtb = v + nVT;
        ushort* at  = vtb + nVT;

        gemm_sync<<<dim3(QD / 128, S_LEN / 128), blk, 0, stream>>>(hidden, wq, q, S_LEN, QD, HDIM);
        gemm_sync<<<dim3(KD / 128, S_LEN / 128), blk, 0, stream>>>(hidden, wk, k, S_LEN, KD, HDIM);
        gemm_sync<<<dim3(KD / 128, S_LEN / 128), blk, 0, stream>>>(hidden, wv, v, S_LEN, KD, HDIM);
        rope_kernel<<<(S_LEN * NHEAD * 128) / 256, blk, 0, stream>>>(q, QD, cosb, sinb, NHEAD);
        rope_kernel<<<(S_LEN * NKVH * 128) / 256, blk, 0, stream>>>(k, KD, cosb, sinb, NKVH);
        vtrans_kernel<<<dim3(S_LEN / 64, KD / 64), blk, 0, stream>>>(v, KD, vtb);
        attn_kernel<ushort><<<dim3(S_LEN / 64, NHEAD), blk, 0, stream>>>(q, QD, k, KD, vtb, at);
        gemm_sync_hf<<<dim3(HDIM / 128, S_LEN / 128), blk, 0, stream>>>(at, wo, outp, S_LEN, HDIM, QD);
    }
}

// Round 3
// 546.956 us; speedup vs baseline: 1.1538x; 1.0289x over previous
//
#include <hip/hip_runtime.h>
#include <stdint.h>

// Gemma2 attention (B=1). Global tensors are FLOAT32; MFMA compute is bf16.
#define S_LEN 2048
#define HDIM  3584
#define NHEAD 16
#define NKVH  8
#define DHEAD 256
#define QD    (NHEAD * DHEAD)   // 4096
#define KD    (NKVH * DHEAD)    // 2048
#define QKVD  (QD + 2 * KD)     // 8192
#define WINDOW 1024
#define MASK_VAL (-1e9f)

typedef __bf16 bf16x8 __attribute__((ext_vector_type(8)));
typedef float  f32x4  __attribute__((ext_vector_type(4)));

__device__ __forceinline__ float bf2f(ushort u) {
    union { uint32_t i; float f; } v; v.i = ((uint32_t)u) << 16; return v.f;
}
__device__ __forceinline__ ushort f2bf(float f) {
    union { float f; uint32_t i; } v; v.f = f;
    uint32_t r = (v.i + 0x7FFF + ((v.i >> 16) & 1)) >> 16;  // RNE
    return (ushort)r;
}
__device__ __forceinline__ void gll16(const ushort* g, ushort* l) {
    __builtin_amdgcn_global_load_lds(
        (const __attribute__((address_space(1))) void*)g,
        (__attribute__((address_space(3))) void*)l, 16, 0, 0);
}

// ---------------------------------------------------------------------------
// Fused f32->bf16 convert for hidden + wq + wk + wv + wo (Tier A).
// ---------------------------------------------------------------------------
#define N_H8  (S_LEN * HDIM / 8)       // 917504
#define N_WQ8 (QD * HDIM / 8)          // 1835008
#define N_WK8 (KD * HDIM / 8)          // 917504
#define N_WO8 (HDIM * QD / 8)          // 1835008
#define N_CVT (N_H8 + N_WQ8 + 2 * N_WK8 + N_WO8)

__global__ __launch_bounds__(256) void cvt5_kernel(
    const float* __restrict__ hid, const float* __restrict__ wq,
    const float* __restrict__ wk,  const float* __restrict__ wv,
    const float* __restrict__ wo,
    ushort* __restrict__ hb, ushort* __restrict__ wb, ushort* __restrict__ ob)
{
    int j = blockIdx.x * blockDim.x + threadIdx.x;
    const float* s; ushort* d;
    if (j < N_H8)                { s = hid; d = hb; }
    else if ((j -= N_H8) < N_WQ8)  { s = wq; d = wb; }
    else if ((j -= N_WQ8) < N_WK8) { s = wk; d = wb + (size_t)QD * HDIM; }
    else if ((j -= N_WK8) < N_WK8) { s = wv; d = wb + (size_t)(QD + KD) * HDIM; }
    else                         { j -= N_WK8; s = wo; d = ob; }
    float4 a = ((const float4*)s)[(size_t)j * 2];
    float4 b = ((const float4*)s)[(size_t)j * 2 + 1];
    ushort tmp[8];
    tmp[0] = f2bf(a.x); tmp[1] = f2bf(a.y); tmp[2] = f2bf(a.z); tmp[3] = f2bf(a.w);
    tmp[4] = f2bf(b.x); tmp[5] = f2bf(b.y); tmp[6] = f2bf(b.z); tmp[7] = f2bf(b.w);
    ((uint4*)d)[j] = *(uint4*)tmp;
}

// single-tensor convert (Tier B)
__global__ __launch_bounds__(256) void cvt_kernel(const float* __restrict__ src,
                                                  ushort* __restrict__ dst, int n8)
{
    int i = blockIdx.x * blockDim.x + threadIdx.x;
    if (i >= n8) return;
    float4 a = ((const float4*)src)[i * 2];
    float4 b = ((const float4*)src)[i * 2 + 1];
    ushort tmp[8];
    tmp[0] = f2bf(a.x); tmp[1] = f2bf(a.y); tmp[2] = f2bf(a.z); tmp[3] = f2bf(a.w);
    tmp[4] = f2bf(b.x); tmp[5] = f2bf(b.y); tmp[6] = f2bf(b.z); tmp[7] = f2bf(b.w);
    ((uint4*)dst)[i] = *(uint4*)tmp;
}

// ---------------------------------------------------------------------------
// f32 tile staging with convert, bank-swizzled (legacy 128x32 layout).
// ---------------------------------------------------------------------------
__device__ __forceinline__ void stage_f32(ushort* __restrict__ dst,
                                          const float* __restrict__ src,
                                          int r0, int K, int kt, int t)
{
#pragma unroll
    for (int i = 0; i < 4; i++) {
        int g = t + i * 256;
        int row = g >> 3, c = g & 7;
        float4 f = *(const float4*)(src + (size_t)(r0 + row) * K + kt + c * 4);
        ushort4 u;
        u.x = f2bf(f.x); u.y = f2bf(f.y); u.z = f2bf(f.z); u.w = f2bf(f.w);
        int cl = (c >> 1) ^ ((row >> 1) & 3);
        *(ushort4*)(dst + row * 32 + cl * 8 + (c & 1) * 4) = u;
    }
}

// ===========================================================================
// BMx256 GEMM, 2-barrier/K-tile schedule: C[M,N] = A[M,K]*B[N,K]^T, bf16 in.
// 512 threads = 8 waves (2M x 4N); wave tile (BM/2)x64; BK=64; LDS dbuf.
// Each K-tile: load every fragment ONCE (gray-code quadrants), MFMA order
//   P1=A0*B0, P2=A0*B1, P3=A1*B1, P4=A1*B0  (K ascending inside each P).
// Counted vmcnt (4 for BM=256, 3 for BM=128) + 2 barriers per tile; frag
// lgkm waits left to the compiler (counted, overlap MFMA). Stages into
// buf^1 only after the top barrier (all prior reads of buf^1 drained by
// each wave's own MFMA-use waits). LDS chunk sc holds logical chunk
// sc^(row&7) via pre-swizzled gll source; ds_read conflict-free.
// ===========================================================================
#define VM4   asm volatile("s_waitcnt vmcnt(4)" ::: "memory")
#define VM3   asm volatile("s_waitcnt vmcnt(3)" ::: "memory")
#define VM0   asm volatile("s_waitcnt vmcnt(0)" ::: "memory")
#define MFEN  asm volatile("" ::: "memory")

#define MMAQ(AF, BF, QM, QN) do {                                              \
    __builtin_amdgcn_s_setprio(1);                                             \
    _Pragma("unroll") for (int i_ = 0; i_ < MIQ; i_++)                         \
      _Pragma("unroll") for (int n_ = 0; n_ < 2; n_++) {                       \
        acc[(QM) * MIQ + i_][(QN) * 2 + n_] = __builtin_amdgcn_mfma_f32_16x16x32_bf16( \
            AF[i_][0], BF[n_][0], acc[(QM) * MIQ + i_][(QN) * 2 + n_], 0, 0, 0);       \
        acc[(QM) * MIQ + i_][(QN) * 2 + n_] = __builtin_amdgcn_mfma_f32_16x16x32_bf16( \
            AF[i_][1], BF[n_][1], acc[(QM) * MIQ + i_][(QN) * 2 + n_], 0, 0, 0);       \
      }                                                                        \
    __builtin_amdgcn_s_setprio(0);                                             \
  } while (0)

template <int BM, typename TC>
__global__ __launch_bounds__(512, 2) void gemm256(const ushort* __restrict__ A,
                                                  const ushort* __restrict__ B,
                                                  TC* __restrict__ C,
                                                  int M, int N, int K)
{
    constexpr int WM  = BM / 2;    // wave M-tile (128 or 64)
    constexpr int MIQ = WM / 32;   // mi per quadrant (4 or 2)
    __shared__ __align__(16) ushort As[2][BM * 64];
    __shared__ __align__(16) ushort Bs[2][256 * 64];

    const int t    = threadIdx.x;
    const int lane = t & 63;
    const int w    = t >> 6;          // 0..7
    const int l15  = lane & 15;
    const int quad = lane >> 4;
    const int m0   = blockIdx.y * BM;
    const int n0   = blockIdx.x * 256;
    const int wm   = (w >> 2) * WM;
    const int wn   = (w & 3) * 64;
    const int lr8  = lane >> 3;       // row within 8-row wave chunk
    const int sc   = lane & 7;        // stored 16B chunk

    f32x4 acc[2 * MIQ][4] = {};
    bf16x8 a0f[MIQ][2], a1f[MIQ][2], b0f[2][2], b1f[2][2];

    auto readA = [&](bf16x8 (&af)[MIQ][2], int buf, int qm) {
#pragma unroll
        for (int i = 0; i < MIQ; i++) {
            int R = wm + qm * (WM / 2) + i * 16 + l15;
            af[i][0] = *(const bf16x8*)(&As[buf][R * 64 + ((quad ^ (R & 7)) * 8)]);
            af[i][1] = *(const bf16x8*)(&As[buf][R * 64 + (((4 + quad) ^ (R & 7)) * 8)]);
        }
    };
    auto readB = [&](bf16x8 (&bf)[2][2], int buf, int qn) {
#pragma unroll
        for (int n = 0; n < 2; n++) {
            int R = wn + qn * 32 + n * 16 + l15;
            bf[n][0] = *(const bf16x8*)(&Bs[buf][R * 64 + ((quad ^ (R & 7)) * 8)]);
            bf[n][1] = *(const bf16x8*)(&Bs[buf][R * 64 + (((4 + quad) ^ (R & 7)) * 8)]);
        }
    };

    // half-tile staging (16KB for BM=256 A / B; 8KB for BM=128 A).
    // A-q<qm>: BM=256 rows {qm*64..+63} u {128+qm*64..+63} (2 gll/thread);
    //          BM=128 rows {qm*32..+31} u {64+qm*32..+31}  (1 gll/thread).
    // B-q<qn>: rows {s*64+qn*32..+31 : s=0..3} (2 gll/thread).
    auto stageA = [&](int buf, int qm, int tile) {
#pragma unroll
        for (int i = 0; i < BM / 128; i++) {
            int cb = (i * 8 + w) * 8;
            int lr = cb + lr8;
            int row, rb;
            if constexpr (BM == 256) {
                row = qm * 64 + (lr & 63) + ((lr >> 6) << 7);
                rb  = qm * 64 + (cb & 63) + ((cb >> 6) << 7);
            } else {
                row = qm * 32 + (lr & 31) + ((lr >> 5) << 6);
                rb  = qm * 32 + (cb & 31) + ((cb >> 5) << 6);
            }
            gll16(A + (size_t)(m0 + row) * K + tile * 64 + ((sc ^ lr8) * 8),
                  &As[buf][rb * 64]);
        }
    };
    auto stageB = [&](int buf, int qn, int tile) {
#pragma unroll
        for (int i = 0; i < 2; i++) {
            int cb  = (i * 8 + w) * 8;
            int lr  = cb + lr8;
            int row = ((lr >> 5) << 6) + qn * 32 + (lr & 31);
            int rb  = ((cb >> 5) << 6) + qn * 32 + (cb & 31);
            gll16(B + (size_t)(n0 + row) * K + tile * 64 + ((sc ^ lr8) * 8),
                  &Bs[buf][rb * 64]);
        }
    };

    const int NT = K >> 6;

    // Prologue: stage tile 0 (order a0,b0,b1,a1), wait a0+b0 landed.
    stageA(0, 0, 0); stageB(0, 0, 0); stageB(0, 1, 0); stageA(0, 1, 0);
    if constexpr (BM == 256) { VM4; } else { VM3; }
    __builtin_amdgcn_s_barrier(); MFEN;

    for (int T = 0; T < NT; ++T) {
        const int buf = T & 1;
        const bool pf = (T + 1 < NT);
        // ---- first half: quadrants of A0/B0 ----
        readB(b0f, buf, 0);
        readA(a0f, buf, 0);
        if (pf) { stageA(buf ^ 1, 0, T + 1); stageB(buf ^ 1, 0, T + 1); }
        MMAQ(a0f, b0f, 0, 0);                                    // P1
        if (pf) { if constexpr (BM == 256) { VM4; } else { VM3; } } else { VM0; }
        __builtin_amdgcn_s_barrier(); MFEN;
        // ---- second half: B1, A1 ----
        readB(b1f, buf, 1);
        if (pf) { stageB(buf ^ 1, 1, T + 1); stageA(buf ^ 1, 1, T + 1); }
        MMAQ(a0f, b1f, 0, 1);                                    // P2
        readA(a1f, buf, 1);
        MMAQ(a1f, b1f, 1, 1);                                    // P3
        MMAQ(a1f, b0f, 1, 0);                                    // P4
        if (pf) {
            if constexpr (BM == 256) { VM4; } else { VM3; }
            __builtin_amdgcn_s_barrier(); MFEN;
        }
    }

    // Epilogue C-write (same lane mapping as before; K-order identical).
#pragma unroll
    for (int qm = 0; qm < 2; qm++)
#pragma unroll
      for (int i = 0; i < MIQ; i++)
#pragma unroll
        for (int qn = 0; qn < 2; qn++)
#pragma unroll
          for (int n = 0; n < 2; n++)
#pragma unroll
            for (int r = 0; r < 4; r++) {
                int row = m0 + wm + qm * (WM / 2) + i * 16 + quad * 4 + r;
                int col = n0 + wn + qn * 32 + n * 16 + l15;
                float val = acc[qm * MIQ + i][qn * 2 + n][r];
                if constexpr (sizeof(TC) == 4) C[(size_t)row * N + col] = val;
                else                           C[(size_t)row * N + col] = f2bf(val);
            }
}

// ---------------------------------------------------------------------------
// Legacy 128x128 GEMM (Tier B QKV: f32 A staging path).
// ---------------------------------------------------------------------------
template <typename TA, typename TC>
__global__ __launch_bounds__(256) void gemm_async(const TA* __restrict__ A,
                                                  const ushort* __restrict__ B,
                                                  TC* __restrict__ C,
                                                  int M, int N, int K)
{
    __shared__ __align__(16) ushort As[128 * 32];
    __shared__ __align__(16) ushort Bs[128 * 32];

    const int t    = threadIdx.x;
    const int lane = t & 63;
    const int w    = t >> 6;
    const int l15  = lane & 15;
    const int quad = lane >> 4;
    const int m0   = blockIdx.y * 128;
    const int n0   = blockIdx.x * 128;
    const int wm   = (w >> 1) * 64;
    const int wn   = (w & 1) * 64;
    const int srow = lane >> 2;
    const int scol = ((lane & 3) ^ ((srow >> 1) & 3)) * 8;
    const int sw   = (l15 >> 1) & 3;

    f32x4 acc[4][4] = {};

    for (int kt = 0; kt < K; kt += 32) {
        __syncthreads();
#pragma unroll
        for (int j = 0; j < 2; j++) {
            const int rb = w * 32 + j * 16;
            if constexpr (sizeof(TA) == 2) {
                gll16((const ushort*)A + (size_t)(m0 + rb + srow) * K + kt + scol,
                      As + rb * 32);
            }
            gll16(B + (size_t)(n0 + rb + srow) * K + kt + scol, Bs + rb * 32);
        }
        if constexpr (sizeof(TA) == 4)
            stage_f32(As, (const float*)A, m0, K, kt, t);
        __syncthreads();

        bf16x8 a[4], b[4];
#pragma unroll
        for (int mi = 0; mi < 4; mi++)
            a[mi] = *(const bf16x8*)(As + (wm + mi * 16 + l15) * 32 + (quad ^ sw) * 8);
#pragma unroll
        for (int ni = 0; ni < 4; ni++)
            b[ni] = *(const bf16x8*)(Bs + (wn + ni * 16 + l15) * 32 + (quad ^ sw) * 8);
#pragma unroll
        for (int mi = 0; mi < 4; mi++)
#pragma unroll
            for (int ni = 0; ni < 4; ni++)
                acc[mi][ni] = __builtin_amdgcn_mfma_f32_16x16x32_bf16(
                    a[mi], b[ni], acc[mi][ni], 0, 0, 0);
    }

#pragma unroll
    for (int mi = 0; mi < 4; mi++)
#pragma unroll
        for (int ni = 0; ni < 4; ni++)
#pragma unroll
            for (int r = 0; r < 4; r++) {
                int row = m0 + wm + mi * 16 + quad * 4 + r;
                int col = n0 + wn + ni * 16 + l15;
                float val = acc[mi][ni][r];
                if constexpr (sizeof(TC) == 4) C[(size_t)row * N + col] = val;
                else                           C[(size_t)row * N + col] = f2bf(val);
            }
}

// ---------------------------------------------------------------------------
// Slow-fallback GEMMs (Tier C), swizzle-consistent.
// ---------------------------------------------------------------------------
__global__ __launch_bounds__(256) void gemm_sync(const float* __restrict__ A,
                                                 const float* __restrict__ B,
                                                 ushort* __restrict__ C,
                                                 int M, int N, int K)
{
    __shared__ __align__(16) ushort As[128 * 32];
    __shared__ __align__(16) ushort Bs[128 * 32];
    const int t = threadIdx.x, lane = t & 63, w = t >> 6;
    const int l15 = lane & 15, quad = lane >> 4;
    const int sw = (l15 >> 1) & 3;
    const int m0 = blockIdx.y * 128, n0 = blockIdx.x * 128;
    const int wm = (w >> 1) * 64, wn = (w & 1) * 64;
    f32x4 acc[4][4] = {};
    for (int kt = 0; kt < K; kt += 32) {
        __syncthreads();
        stage_f32(As, A, m0, K, kt, t);
        stage_f32(Bs, B, n0, K, kt, t);
        __syncthreads();
        bf16x8 a[4], b[4];
#pragma unroll
        for (int mi = 0; mi < 4; mi++)
            a[mi] = *(const bf16x8*)(As + (wm + mi * 16 + l15) * 32 + (quad ^ sw) * 8);
#pragma unroll
        for (int ni = 0; ni < 4; ni++)
            b[ni] = *(const bf16x8*)(Bs + (wn + ni * 16 + l15) * 32 + (quad ^ sw) * 8);
#pragma unroll
        for (int mi = 0; mi < 4; mi++)
#pragma unroll
            for (int ni = 0; ni < 4; ni++)
                acc[mi][ni] = __builtin_amdgcn_mfma_f32_16x16x32_bf16(
                    a[mi], b[ni], acc[mi][ni], 0, 0, 0);
    }
#pragma unroll
    for (int mi = 0; mi < 4; mi++)
#pragma unroll
        for (int ni = 0; ni < 4; ni++)
#pragma unroll
            for (int r = 0; r < 4; r++)
                C[(size_t)(m0 + wm + mi * 16 + quad * 4 + r) * N +
                  n0 + wn + ni * 16 + l15] = f2bf(acc[mi][ni][r]);
}

__global__ __launch_bounds__(256) void gemm_sync_hf(const ushort* __restrict__ A,
                                                    const float* __restrict__ B,
                                                    float* __restrict__ C,
                                                    int M, int N, int K)
{
    __shared__ __align__(16) ushort As[128 * 32];
    __shared__ __align__(16) ushort Bs[128 * 32];
    const int t = threadIdx.x, lane = t & 63, w = t >> 6;
    const int l15 = lane & 15, quad = lane >> 4;
    const int sw = (l15 >> 1) & 3;
    const int m0 = blockIdx.y * 128, n0 = blockIdx.x * 128;
    const int wm = (w >> 1) * 64, wn = (w & 1) * 64;
    f32x4 acc[4][4] = {};
    for (int kt = 0; kt < K; kt += 32) {
        __syncthreads();
#pragma unroll
        for (int i = 0; i < 2; i++) {
            int g = t + i * 256;
            int row = g >> 2, c = g & 3;
            int cl = c ^ ((row >> 1) & 3);
            *(uint4*)(As + row * 32 + cl * 8) =
                *(const uint4*)(A + (size_t)(m0 + row) * K + kt + c * 8);
        }
        stage_f32(Bs, B, n0, K, kt, t);
        __syncthreads();
        bf16x8 a[4], b[4];
#pragma unroll
        for (int mi = 0; mi < 4; mi++)
            a[mi] = *(const bf16x8*)(As + (wm + mi * 16 + l15) * 32 + (quad ^ sw) * 8);
#pragma unroll
        for (int ni = 0; ni < 4; ni++)
            b[ni] = *(const bf16x8*)(Bs + (wn + ni * 16 + l15) * 32 + (quad ^ sw) * 8);
#pragma unroll
        for (int mi = 0; mi < 4; mi++)
#pragma unroll
            for (int ni = 0; ni < 4; ni++)
                acc[mi][ni] = __builtin_amdgcn_mfma_f32_16x16x32_bf16(
                    a[mi], b[ni], acc[mi][ni], 0, 0, 0);
    }
#pragma unroll
    for (int mi = 0; mi < 4; mi++)
#pragma unroll
        for (int ni = 0; ni < 4; ni++)
#pragma unroll
            for (int r = 0; r < 4; r++)
                C[(size_t)(m0 + wm + mi * 16 + quad * 4 + r) * N +
                  n0 + wn + ni * 16 + l15] = acc[mi][ni][r];
}

// ---------------------------------------------------------------------------
// RoPE in-place on rows of stride `stride`, nh heads at column h*256.
// ---------------------------------------------------------------------------
__global__ void rope_kernel(ushort* __restrict__ x, int stride,
                            const float* __restrict__ cosb,
                            const float* __restrict__ sinb, int nh)
{
    int idx  = blockIdx.x * blockDim.x + threadIdx.x;
    int d    = idx & 127;
    int rest = idx >> 7;
    int h    = rest & (nh - 1);
    int s    = rest / nh;
    size_t base = (size_t)s * stride + h * DHEAD;
    float c  = cosb[s * DHEAD + d];
    float sn = sinb[s * DHEAD + d];
    float x1 = bf2f(x[base + d]);
    float x2 = bf2f(x[base + d + 128]);
    x[base + d]       = f2bf(x1 * c - x2 * sn);
    x[base + d + 128] = f2bf(x2 * c + x1 * sn);
}

// ---------------------------------------------------------------------------
// Transpose V rows (stride) -> Vt [KD][S_LEN], 64x64 tiles.
// ---------------------------------------------------------------------------
__global__ __launch_bounds__(256) void vtrans_kernel(const ushort* __restrict__ v,
                                                     int stride,
                                                     ushort* __restrict__ vt)
{
    __shared__ __align__(16) ushort tile[64][72];
    int s0 = blockIdx.x * 64, c0 = blockIdx.y * 64;
    int t  = threadIdx.x;
#pragma unroll
    for (int i = 0; i < 2; i++) {
        int cI = t + i * 256;
        int row = cI >> 3, c8 = cI & 7;
        *(uint4*)&tile[row][c8 * 8] =
            *(const uint4*)(v + (size_t)(s0 + row) * stride + c0 + c8 * 8);
    }
    __syncthreads();
#pragma unroll
    for (int i = 0; i < 2; i++) {
        int cI = t + i * 256;
        int crow = cI >> 3, s8 = cI & 7;
        ushort tmp[8];
#pragma unroll
        for (int j = 0; j < 8; j++) tmp[j] = tile[s8 * 8 + j][crow];
        *(uint4*)(vt + (size_t)(c0 + crow) * S_LEN + s0 + s8 * 8) = *(uint4*)tmp;
    }
}

// ---------------------------------------------------------------------------
// Flash attention, block = 64 q-rows x 1 head, 4 waves (16 rows each).
// ---------------------------------------------------------------------------
template <typename TO>
__global__ __launch_bounds__(256) void attn_kernel(const ushort* __restrict__ qr, int qstride,
                                                   const ushort* __restrict__ kr, int kstride,
                                                   const ushort* __restrict__ vt,
                                                   TO* __restrict__ out)
{
    __shared__ __align__(16) ushort Ks[64 * 256];   // [key][d] 32KB
    __shared__ __align__(16) ushort Vs[256 * 64];   // [d][key] 32KB
    __shared__ __align__(16) ushort Ps[4][16 * 68]; // padded, 8.5KB

    const int t    = threadIdx.x;
    const int lane = t & 63;
    const int w    = t >> 6;
    const int l15  = lane & 15;
    const int quad = lane >> 4;
    const int q0B  = blockIdx.x * 64;
    const int q0   = q0B + w * 16;
    const int h    = blockIdx.y;
    const int kvh  = h >> 1;  // GROUPS = 2

    bf16x8 aQ[8];
    const ushort* qrow = qr + (size_t)(q0 + l15) * qstride + h * DHEAD;
#pragma unroll
    for (int kk = 0; kk < 8; kk++)
        aQ[kk] = *(const bf16x8*)(qrow + kk * 32 + quad * 8);

    f32x4 oacc[16] = {};
    float m_i[4], l_i[4];
#pragma unroll
    for (int r = 0; r < 4; r++) { m_i[r] = -1e30f; l_i[r] = 0.f; }

    int km = q0B - (WINDOW - 1);
    if (km < 0) km = 0;
    km &= ~63;

    for (int kb = km; kb < q0B + 64; kb += 64) {
        __syncthreads();
#pragma unroll
        for (int i = 0; i < 8; i++) {
            int base = i * 256 + w * 64;
            int idx  = base + lane;
            int row = idx >> 5, c = idx & 31;
            int cs = c ^ (row & 7);
            gll16(kr + (size_t)(kb + row) * kstride + kvh * DHEAD + cs * 8,
                  Ks + base * 8);
        }
#pragma unroll
        for (int i = 0; i < 8; i++) {
            int base = i * 256 + w * 64;
            int idx  = base + lane;
            int row = idx >> 3, c = idx & 7;
            int cs = c ^ (row & 7);
            gll16(vt + (size_t)(kvh * DHEAD + row) * S_LEN + kb + cs * 8,
                  Vs + base * 8);
        }
        __syncthreads();

        // ---- QK^T: S[16q][64k] ----
        f32x4 sc[4] = {};
#pragma unroll
        for (int ni = 0; ni < 4; ni++) {
            int row = ni * 16 + l15;
#pragma unroll
            for (int kk = 0; kk < 8; kk++) {
                int cp = (kk * 4 + quad) ^ (row & 7);
                bf16x8 bk = *(const bf16x8*)(Ks + row * 256 + cp * 8);
                sc[ni] = __builtin_amdgcn_mfma_f32_16x16x32_bf16(aQ[kk], bk, sc[ni], 0, 0, 0);
            }
        }

        // ---- softcap + mask + online softmax ----
        const bool interior = (kb + 63 <= q0) && (q0 + 15 - kb < WINDOW);
        float p[4][4];
        float mt[4] = { -1e30f, -1e30f, -1e30f, -1e30f };
        if (interior) {
#pragma unroll
            for (int ni = 0; ni < 4; ni++)
#pragma unroll
                for (int r = 0; r < 4; r++) {
                    float e = __expf(sc[ni][r] * 0.0025f);
                    float x = 50.f * (e - 1.f) * __builtin_amdgcn_rcpf(e + 1.f);
                    p[ni][r] = x;
                    mt[r] = fmaxf(mt[r], x);
                }
        } else {
#pragma unroll
            for (int ni = 0; ni < 4; ni++)
#pragma unroll
                for (int r = 0; r < 4; r++) {
                    int qi = q0 + quad * 4 + r;
                    int ki = kb + ni * 16 + l15;
                    float e = __expf(sc[ni][r] * 0.0025f);
                    float x = 50.f * (e - 1.f) * __builtin_amdgcn_rcpf(e + 1.f);
                    bool ok = (ki <= qi) && (qi - ki < WINDOW);
                    x = ok ? x : MASK_VAL;
                    p[ni][r] = x;
                    mt[r] = fmaxf(mt[r], x);
                }
        }
#pragma unroll
        for (int r = 0; r < 4; r++)
#pragma unroll
            for (int off = 1; off < 16; off <<= 1)
                mt[r] = fmaxf(mt[r], __shfl_xor(mt[r], off));

        float alpha[4], rs[4];
#pragma unroll
        for (int r = 0; r < 4; r++) {
            float mn = fmaxf(m_i[r], mt[r]);
            alpha[r] = __expf(m_i[r] - mn);
            m_i[r] = mn;
            rs[r] = 0.f;
        }
#pragma unroll
        for (int ni = 0; ni < 4; ni++)
#pragma unroll
            for (int r = 0; r < 4; r++) {
                float pe = __expf(p[ni][r] - m_i[r]);
                rs[r] += pe;
                Ps[w][(quad * 4 + r) * 68 + ni * 16 + l15] = f2bf(pe);
            }
#pragma unroll
        for (int r = 0; r < 4; r++) {
#pragma unroll
            for (int off = 1; off < 16; off <<= 1)
                rs[r] += __shfl_xor(rs[r], off);
            l_i[r] = l_i[r] * alpha[r] + rs[r];
        }
#pragma unroll
        for (int nd = 0; nd < 16; nd++)
#pragma unroll
            for (int r = 0; r < 4; r++)
                oacc[nd][r] *= alpha[r];

        __asm__ volatile("s_waitcnt lgkmcnt(0)" ::: "memory");

        // ---- PV ----
        bf16x8 aP[2];
#pragma unroll
        for (int kk = 0; kk < 2; kk++)
            aP[kk] = *(const bf16x8*)(&Ps[w][l15 * 68 + kk * 32 + quad * 8]);
#pragma unroll
        for (int nd = 0; nd < 16; nd++) {
            int row = nd * 16 + l15;
#pragma unroll
            for (int kk = 0; kk < 2; kk++) {
                int cp = (kk * 4 + quad) ^ (row & 7);
                bf16x8 bv = *(const bf16x8*)(Vs + row * 64 + cp * 8);
                oacc[nd] = __builtin_amdgcn_mfma_f32_16x16x32_bf16(aP[kk], bv, oacc[nd], 0, 0, 0);
            }
        }
    }

#pragma unroll
    for (int r = 0; r < 4; r++) {
        float invl = __builtin_amdgcn_rcpf(l_i[r]);
#pragma unroll
        for (int nd = 0; nd < 16; nd++) {
            int qi = q0 + quad * 4 + r;
            int d  = nd * 16 + l15;
            float val = oacc[nd][r] * invl;
            if constexpr (sizeof(TO) == 4) out[(size_t)qi * QD + h * DHEAD + d] = val;
            else                           out[(size_t)qi * QD + h * DHEAD + d] = f2bf(val);
        }
    }
}

// ---------------------------------------------------------------------------
extern "C" void kernel_launch(void* const* d_in, const int* in_sizes, int n_in,
                              void* d_out, int out_size, void* d_ws, size_t ws_size,
                              hipStream_t stream)
{
    const float* hidden = (const float*)d_in[0];
    const float* cosb   = (const float*)d_in[1];
    const float* sinb   = (const float*)d_in[2];
    const float* wq     = (const float*)d_in[3];
    const float* wk     = (const float*)d_in[4];
    const float* wv     = (const float*)d_in[5];
    const float* wo     = (const float*)d_in[6];
    float* outp = (float*)d_out;

    const size_t nH   = (size_t)S_LEN * HDIM;
    const size_t nWQ  = (size_t)QD * HDIM;
    const size_t nWK  = (size_t)KD * HDIM;
    const size_t nWB  = (size_t)QKVD * HDIM;
    const size_t nWO  = (size_t)HDIM * QD;
    const size_t nQKV = (size_t)S_LEN * QKVD;
    const size_t nAT  = (size_t)S_LEN * QD;
    const size_t nVT  = (size_t)S_LEN * KD;

    dim3 blk(256);
    dim3 blk512(512);
    const size_t needA = (nWB + nQKV + nH + nWO) * 2;
    const size_t needB = (nWB + nQKV) * 2;

    if (ws_size >= needA) {
        ushort* wb  = (ushort*)d_ws;
        ushort* qkv = wb + nWB;
        ushort* hb  = qkv + nQKV;
        ushort* ob  = hb + nH;
        ushort* at  = wb;                      // alias (wb dead after QKV GEMM)
        ushort* vtb = wb + nAT;

        cvt5_kernel<<<(N_CVT + 255) / 256, blk, 0, stream>>>(hidden, wq, wk, wv, wo, hb, wb, ob);
        gemm256<256, ushort><<<dim3(QKVD / 256, S_LEN / 256), blk512, 0, stream>>>(
            hb, wb, qkv, S_LEN, QKVD, HDIM);
        rope_kernel<<<(S_LEN * NHEAD * 128) / 256, blk, 0, stream>>>(qkv, QKVD, cosb, sinb, NHEAD);
        rope_kernel<<<(S_LEN * NKVH * 128) / 256, blk, 0, stream>>>(qkv + QD, QKVD, cosb, sinb, NKVH);
        vtrans_kernel<<<dim3(S_LEN / 64, KD / 64), blk, 0, stream>>>(qkv + QD + KD, QKVD, vtb);
        attn_kernel<ushort><<<dim3(S_LEN / 64, NHEAD), blk, 0, stream>>>(
            qkv, QKVD, qkv + QD, QKVD, vtb, at);
        gemm256<128, float><<<dim3(HDIM / 256, S_LEN / 128), blk512, 0, stream>>>(
            at, ob, outp, S_LEN, HDIM, QD);
    } else if (ws_size >= needB) {
        ushort* wb  = (ushort*)d_ws;
        ushort* qkv = wb + nWB;
        ushort* at  = wb;
        ushort* vtb = wb + nAT;
        ushort* ob  = wb + nAT + nVT;

        cvt_kernel<<<(int)(nWQ / 8 / 256), blk, 0, stream>>>(wq, wb, (int)(nWQ / 8));
        cvt_kernel<<<(int)(nWK / 8 / 256), blk, 0, stream>>>(wk, wb + nWQ, (int)(nWK / 8));
        cvt_kernel<<<(int)(nWK / 8 / 256), blk, 0, stream>>>(wv, wb + nWQ + nWK, (int)(nWK / 8));
        gemm_async<float, ushort><<<dim3(QKVD / 128, S_LEN / 128), blk, 0, stream>>>(
            hidden, wb, qkv, S_LEN, QKVD, HDIM);
        cvt_kernel<<<(int)(nWO / 8 / 256), blk, 0, stream>>>(wo, ob, (int)(nWO / 8));
        rope_kernel<<<(S_LEN * NHEAD * 128) / 256, blk, 0, stream>>>(qkv, QKVD, cosb, sinb, NHEAD);
        rope_kernel<<<(S_LEN * NKVH * 128) / 256, blk, 0, stream>>>(qkv + QD, QKVD, cosb, sinb, NKVH);
        vtrans_kernel<<<dim3(S_LEN / 64, KD / 64), blk, 0, stream>>>(qkv + QD + KD, QKVD, vtb);
        attn_kernel<ushort><<<dim3(S_LEN / 64, NHEAD), blk, 0, stream>>>(
            qkv, QKVD, qkv + QD, QKVD, vtb, at);
        gemm256<128, float><<<dim3(HDIM / 256, S_LEN / 128), blk512, 0, stream>>>(
            at, ob, outp, S_LEN, HDIM, QD);
    } else {
        ushort* q   = (ushort*)d_ws;
        ushort* k   = q + nAT;
        ushort* v   = k + nVT;
        ushort* vtb = v + nVT;
        ushort* at  = vtb + nVT;

        gemm_sync<<<dim3(QD / 128, S_LEN / 128), blk, 0, stream>>>(hidden, wq, q, S_LEN, QD, HDIM);
        gemm_sync<<<dim3(KD / 128, S_LEN / 128), blk, 0, stream>>>(hidden, wk, k, S_LEN, KD, HDIM);
        gemm_sync<<<dim3(KD / 128, S_LEN / 128), blk, 0, stream>>>(hidden, wv, v, S_LEN, KD, HDIM);
        rope_kernel<<<(S_LEN * NHEAD * 128) / 256, blk, 0, stream>>>(q, QD, cosb, sinb, NHEAD);
        rope_kernel<<<(S_LEN * NKVH * 128) / 256, blk, 0, stream>>>(k, KD, cosb, sinb, NKVH);
        vtrans_kernel<<<dim3(S_LEN / 64, KD / 64), blk, 0, stream>>>(v, KD, vtb);
        attn_kernel<ushort><<<dim3(S_LEN / 64, NHEAD), blk, 0, stream>>>(q, QD, k, KD, vtb, at);
        gemm_sync_hf<<<dim3(HDIM / 128, S_LEN / 128), blk, 0, stream>>>(at, wo, outp, S_LEN, HDIM, QD);
    }
}

// Round 5
// 525.173 us; speedup vs baseline: 1.2017x; 1.0415x over previous
//
#include <hip/hip_runtime.h>
#include <stdint.h>

// Gemma2 attention (B=1). Global tensors are FLOAT32; MFMA compute is bf16.
#define S_LEN 2048
#define HDIM  3584
#define NHEAD 16
#define NKVH  8
#define DHEAD 256
#define QD    (NHEAD * DHEAD)   // 4096
#define KD    (NKVH * DHEAD)    // 2048
#define QKVD  (QD + 2 * KD)     // 8192
#define WINDOW 1024
#define MASK_VAL (-1e9f)

typedef __bf16 bf16x8 __attribute__((ext_vector_type(8)));
typedef float  f32x4  __attribute__((ext_vector_type(4)));

__device__ __forceinline__ float bf2f(ushort u) {
    union { uint32_t i; float f; } v; v.i = ((uint32_t)u) << 16; return v.f;
}
__device__ __forceinline__ ushort f2bf(float f) {
    union { float f; uint32_t i; } v; v.f = f;
    uint32_t r = (v.i + 0x7FFF + ((v.i >> 16) & 1)) >> 16;  // RNE
    return (ushort)r;
}
__device__ __forceinline__ void gll16(const ushort* g, ushort* l) {
    __builtin_amdgcn_global_load_lds(
        (const __attribute__((address_space(1))) void*)g,
        (__attribute__((address_space(3))) void*)l, 16, 0, 0);
}

// ---------------------------------------------------------------------------
// Fused f32->bf16 convert for hidden + wq + wk + wv + wo (Tier A).
// ---------------------------------------------------------------------------
#define N_H8  (S_LEN * HDIM / 8)       // 917504
#define N_WQ8 (QD * HDIM / 8)          // 1835008
#define N_WK8 (KD * HDIM / 8)          // 917504
#define N_WO8 (HDIM * QD / 8)          // 1835008
#define N_CVT (N_H8 + N_WQ8 + 2 * N_WK8 + N_WO8)

__global__ __launch_bounds__(256) void cvt5_kernel(
    const float* __restrict__ hid, const float* __restrict__ wq,
    const float* __restrict__ wk,  const float* __restrict__ wv,
    const float* __restrict__ wo,
    ushort* __restrict__ hb, ushort* __restrict__ wb, ushort* __restrict__ ob)
{
    int j = blockIdx.x * blockDim.x + threadIdx.x;
    const float* s; ushort* d;
    if (j < N_H8)                { s = hid; d = hb; }
    else if ((j -= N_H8) < N_WQ8)  { s = wq; d = wb; }
    else if ((j -= N_WQ8) < N_WK8) { s = wk; d = wb + (size_t)QD * HDIM; }
    else if ((j -= N_WK8) < N_WK8) { s = wv; d = wb + (size_t)(QD + KD) * HDIM; }
    else                         { j -= N_WK8; s = wo; d = ob; }
    float4 a = ((const float4*)s)[(size_t)j * 2];
    float4 b = ((const float4*)s)[(size_t)j * 2 + 1];
    ushort tmp[8];
    tmp[0] = f2bf(a.x); tmp[1] = f2bf(a.y); tmp[2] = f2bf(a.z); tmp[3] = f2bf(a.w);
    tmp[4] = f2bf(b.x); tmp[5] = f2bf(b.y); tmp[6] = f2bf(b.z); tmp[7] = f2bf(b.w);
    ((uint4*)d)[j] = *(uint4*)tmp;
}

// single-tensor convert (Tier B)
__global__ __launch_bounds__(256) void cvt_kernel(const float* __restrict__ src,
                                                  ushort* __restrict__ dst, int n8)
{
    int i = blockIdx.x * blockDim.x + threadIdx.x;
    if (i >= n8) return;
    float4 a = ((const float4*)src)[i * 2];
    float4 b = ((const float4*)src)[i * 2 + 1];
    ushort tmp[8];
    tmp[0] = f2bf(a.x); tmp[1] = f2bf(a.y); tmp[2] = f2bf(a.z); tmp[3] = f2bf(a.w);
    tmp[4] = f2bf(b.x); tmp[5] = f2bf(b.y); tmp[6] = f2bf(b.z); tmp[7] = f2bf(b.w);
    ((uint4*)dst)[i] = *(uint4*)tmp;
}

// ---------------------------------------------------------------------------
// f32 tile staging with convert, bank-swizzled (legacy 128x32 layout).
// ---------------------------------------------------------------------------
__device__ __forceinline__ void stage_f32(ushort* __restrict__ dst,
                                          const float* __restrict__ src,
                                          int r0, int K, int kt, int t)
{
#pragma unroll
    for (int i = 0; i < 4; i++) {
        int g = t + i * 256;
        int row = g >> 3, c = g & 7;
        float4 f = *(const float4*)(src + (size_t)(r0 + row) * K + kt + c * 4);
        ushort4 u;
        u.x = f2bf(f.x); u.y = f2bf(f.y); u.z = f2bf(f.z); u.w = f2bf(f.w);
        int cl = (c >> 1) ^ ((row >> 1) & 3);
        *(ushort4*)(dst + row * 32 + cl * 8 + (c & 1) * 4) = u;
    }
}

// ===========================================================================
// Shared waitcnt helpers for the tiled GEMMs.
// ===========================================================================
#define VM6   asm volatile("s_waitcnt vmcnt(6)" ::: "memory")
#define VM4   asm volatile("s_waitcnt vmcnt(4)" ::: "memory")
#define VM3   asm volatile("s_waitcnt vmcnt(3)" ::: "memory")
#define VM0   asm volatile("s_waitcnt vmcnt(0)" ::: "memory")
#define LGKM0 asm volatile("s_waitcnt lgkmcnt(0)" ::: "memory")
#define MFEN  asm volatile("" ::: "memory")

// ===========================================================================
// 256x256 8-phase GEMM (QKV):  C[M,N] = A[M,K] * B[N,K]^T, bf16 in.
// 512 threads = 8 waves (2M x 4N), wave tile 128x64, BK=64, 128 KiB LDS dbuf.
// Stage/VM6 schedule identical to the round-2 verified kernel; held fragment
// arrays skip redundant re-reads: 24 ds_read_b128/tile/wave (was 32), phases
// 4/8 pure-MFMA. Quadrant order per tile: A0B0, A1*B0, A1B1, A0*B1 (acc
// K-order per cell unchanged -> bit-identical output).
// LDS chunk sc holds logical chunk sc^(row&7) via pre-swizzled gll source.
// ===========================================================================
#define PHASE_A(BUF, AF, BF, LA, LB, QM, QN, STAGE, TWAIT) do {                \
    if (LA) {                                                                  \
      _Pragma("unroll") for (int i_ = 0; i_ < 4; i_++) {                       \
        int R_ = wm + (QM) * 64 + i_ * 16 + l15;                               \
        AF[i_][0] = *(const bf16x8*)(&As[BUF][R_ * 64 + ((quad ^ (R_ & 7)) * 8)]);       \
        AF[i_][1] = *(const bf16x8*)(&As[BUF][R_ * 64 + (((4 + quad) ^ (R_ & 7)) * 8)]); \
      }                                                                        \
    }                                                                          \
    if (LB) {                                                                  \
      _Pragma("unroll") for (int n_ = 0; n_ < 2; n_++) {                       \
        int R_ = wn + (QN) * 32 + n_ * 16 + l15;                               \
        BF[n_][0] = *(const bf16x8*)(&Bs[BUF][R_ * 64 + ((quad ^ (R_ & 7)) * 8)]);       \
        BF[n_][1] = *(const bf16x8*)(&Bs[BUF][R_ * 64 + (((4 + quad) ^ (R_ & 7)) * 8)]); \
      }                                                                        \
    }                                                                          \
    STAGE;                                                                     \
    MFEN;                                                                      \
    __builtin_amdgcn_s_barrier();                                              \
    LGKM0;                                                                     \
    __builtin_amdgcn_s_setprio(1);                                             \
    _Pragma("unroll") for (int i_ = 0; i_ < 4; i_++)                           \
      _Pragma("unroll") for (int n_ = 0; n_ < 2; n_++) {                       \
        acc[(QM) * 4 + i_][(QN) * 2 + n_] = __builtin_amdgcn_mfma_f32_16x16x32_bf16(  \
            AF[i_][0], BF[n_][0], acc[(QM) * 4 + i_][(QN) * 2 + n_], 0, 0, 0);        \
        acc[(QM) * 4 + i_][(QN) * 2 + n_] = __builtin_amdgcn_mfma_f32_16x16x32_bf16(  \
            AF[i_][1], BF[n_][1], acc[(QM) * 4 + i_][(QN) * 2 + n_], 0, 0, 0);        \
      }                                                                        \
    __builtin_amdgcn_s_setprio(0);                                             \
    TWAIT;                                                                     \
    __builtin_amdgcn_s_barrier();                                              \
    MFEN;                                                                      \
  } while (0)

template <typename TC>
__global__ __launch_bounds__(512, 2) void gemm256x256(const ushort* __restrict__ A,
                                                      const ushort* __restrict__ B,
                                                      TC* __restrict__ C,
                                                      int M, int N, int K)
{
    __shared__ __align__(16) ushort As[2][256 * 64];
    __shared__ __align__(16) ushort Bs[2][256 * 64];

    const int t    = threadIdx.x;
    const int lane = t & 63;
    const int w    = t >> 6;          // 0..7
    const int l15  = lane & 15;
    const int quad = lane >> 4;
    const int m0   = blockIdx.y * 256;
    const int n0   = blockIdx.x * 256;
    const int wm   = (w >> 2) * 128;  // 0 / 128
    const int wn   = (w & 3) * 64;    // 0 / 64 / 128 / 192
    const int lr8  = lane >> 3;       // row within 8-row wave chunk
    const int sc   = lane & 7;        // stored 16B chunk

    f32x4 acc[8][4] = {};
    bf16x8 a0f[4][2], a1f[4][2], b0f[2][2], b1f[2][2];

    auto stageA = [&](int buf, int qm, int tile) {
#pragma unroll
        for (int i = 0; i < 2; i++) {
            int cb  = (i * 8 + w) * 8;                         // base local row
            int lr  = cb + lr8;
            int row = qm * 64 + (lr & 63) + ((lr >> 6) << 7);  // tile/LDS row
            int rb  = qm * 64 + (cb & 63) + ((cb >> 6) << 7);  // wave-uniform base
            gll16(A + (size_t)(m0 + row) * K + tile * 64 + ((sc ^ lr8) * 8),
                  &As[buf][rb * 64]);
        }
    };
    auto stageB = [&](int buf, int qn, int tile) {
#pragma unroll
        for (int i = 0; i < 2; i++) {
            int cb  = (i * 8 + w) * 8;
            int lr  = cb + lr8;
            int row = ((lr >> 5) << 6) + qn * 32 + (lr & 31);
            int rb  = ((cb >> 5) << 6) + qn * 32 + (cb & 31);
            gll16(B + (size_t)(n0 + row) * K + tile * 64 + ((sc ^ lr8) * 8),
                  &Bs[buf][rb * 64]);
        }
    };

    // Prologue: stage t0 fully + t1.{B-q0, A-q1}, in steady-state slot order.
    stageB(0, 0, 0);
    stageA(0, 1, 0);
    stageA(0, 0, 0);
    stageB(0, 1, 0);
    stageB(1, 0, 1);
    stageA(1, 1, 1);
    VM6;                               // oldest 3 half-tiles (t0.Bq0,Aq1,Aq0) landed
    __builtin_amdgcn_s_barrier();
    MFEN;

    const int NJ = K >> 7;             // 2 K-tiles (BK=64 each) per iteration
    for (int j = 0; j < NJ; ++j) {
        const int T = 2 * j;
        const bool tl = (j == NJ - 1);
        // tile T from buf0
        PHASE_A(0, a0f, b0f, 1, 1, 0, 0, stageA(1, 0, T + 1), MFEN);
        PHASE_A(0, a1f, b0f, 1, 0, 1, 0, stageB(1, 1, T + 1), if (tl) { VM0; } else { VM6; });
        PHASE_A(0, a1f, b1f, 0, 1, 1, 1, if (!tl) { stageB(0, 0, T + 2); }, MFEN);
        PHASE_A(0, a0f, b1f, 0, 0, 0, 1, if (!tl) { stageA(0, 1, T + 2); }, if (!tl) { VM6; } else { MFEN; });
        // tile T+1 from buf1
        PHASE_A(1, a0f, b0f, 1, 1, 0, 0, if (!tl) { stageA(0, 0, T + 2); }, MFEN);
        PHASE_A(1, a1f, b0f, 1, 0, 1, 0, if (!tl) { stageB(0, 1, T + 2); }, if (!tl) { VM6; } else { MFEN; });
        PHASE_A(1, a1f, b1f, 0, 1, 1, 1, if (!tl) { stageB(1, 0, T + 3); }, MFEN);
        PHASE_A(1, a0f, b1f, 0, 0, 0, 1, if (!tl) { stageA(1, 1, T + 3); }, if (!tl) { VM6; } else { MFEN; });
    }

    // Epilogue C-write.
#pragma unroll
    for (int qm = 0; qm < 2; qm++)
#pragma unroll
      for (int i = 0; i < 4; i++)
#pragma unroll
        for (int qn = 0; qn < 2; qn++)
#pragma unroll
          for (int n = 0; n < 2; n++)
#pragma unroll
            for (int r = 0; r < 4; r++) {
                int row = m0 + wm + qm * 64 + i * 16 + quad * 4 + r;
                int col = n0 + wn + qn * 32 + n * 16 + l15;
                float val = acc[qm * 4 + i][qn * 2 + n][r];
                if constexpr (sizeof(TC) == 4) C[(size_t)row * N + col] = val;
                else                           C[(size_t)row * N + col] = f2bf(val);
            }
}

// ===========================================================================
// BMx256 GEMM, 2-barrier/K-tile schedule (round-3 VERIFIED; used for W_O
// with BM=128 -> 224 blocks). Gray-code quadrants P1=A0B0,P2=A0B1,P3=A1B1,
// P4=A1B0; counted vmcnt (4 for BM=256, 3 for BM=128) + 2 barriers/tile.
// ===========================================================================
#define MMAQ(AF, BF, QM, QN) do {                                              \
    __builtin_amdgcn_s_setprio(1);                                             \
    _Pragma("unroll") for (int i_ = 0; i_ < MIQ; i_++)                         \
      _Pragma("unroll") for (int n_ = 0; n_ < 2; n_++) {                       \
        acc[(QM) * MIQ + i_][(QN) * 2 + n_] = __builtin_amdgcn_mfma_f32_16x16x32_bf16( \
            AF[i_][0], BF[n_][0], acc[(QM) * MIQ + i_][(QN) * 2 + n_], 0, 0, 0);       \
        acc[(QM) * MIQ + i_][(QN) * 2 + n_] = __builtin_amdgcn_mfma_f32_16x16x32_bf16( \
            AF[i_][1], BF[n_][1], acc[(QM) * MIQ + i_][(QN) * 2 + n_], 0, 0, 0);       \
      }                                                                        \
    __builtin_amdgcn_s_setprio(0);                                             \
  } while (0)

template <int BM, typename TC>
__global__ __launch_bounds__(512, 2) void gemm2b(const ushort* __restrict__ A,
                                                 const ushort* __restrict__ B,
                                                 TC* __restrict__ C,
                                                 int M, int N, int K)
{
    constexpr int WM  = BM / 2;    // wave M-tile (128 or 64)
    constexpr int MIQ = WM / 32;   // mi per quadrant (4 or 2)
    __shared__ __align__(16) ushort As[2][BM * 64];
    __shared__ __align__(16) ushort Bs[2][256 * 64];

    const int t    = threadIdx.x;
    const int lane = t & 63;
    const int w    = t >> 6;          // 0..7
    const int l15  = lane & 15;
    const int quad = lane >> 4;
    const int m0   = blockIdx.y * BM;
    const int n0   = blockIdx.x * 256;
    const int wm   = (w >> 2) * WM;
    const int wn   = (w & 3) * 64;
    const int lr8  = lane >> 3;       // row within 8-row wave chunk
    const int sc   = lane & 7;        // stored 16B chunk

    f32x4 acc[2 * MIQ][4] = {};
    bf16x8 a0f[MIQ][2], a1f[MIQ][2], b0f[2][2], b1f[2][2];

    auto readA = [&](bf16x8 (&af)[MIQ][2], int buf, int qm) {
#pragma unroll
        for (int i = 0; i < MIQ; i++) {
            int R = wm + qm * (WM / 2) + i * 16 + l15;
            af[i][0] = *(const bf16x8*)(&As[buf][R * 64 + ((quad ^ (R & 7)) * 8)]);
            af[i][1] = *(const bf16x8*)(&As[buf][R * 64 + (((4 + quad) ^ (R & 7)) * 8)]);
        }
    };
    auto readB = [&](bf16x8 (&bf)[2][2], int buf, int qn) {
#pragma unroll
        for (int n = 0; n < 2; n++) {
            int R = wn + qn * 32 + n * 16 + l15;
            bf[n][0] = *(const bf16x8*)(&Bs[buf][R * 64 + ((quad ^ (R & 7)) * 8)]);
            bf[n][1] = *(const bf16x8*)(&Bs[buf][R * 64 + (((4 + quad) ^ (R & 7)) * 8)]);
        }
    };

    auto stageA = [&](int buf, int qm, int tile) {
#pragma unroll
        for (int i = 0; i < BM / 128; i++) {
            int cb = (i * 8 + w) * 8;
            int lr = cb + lr8;
            int row, rb;
            if constexpr (BM == 256) {
                row = qm * 64 + (lr & 63) + ((lr >> 6) << 7);
                rb  = qm * 64 + (cb & 63) + ((cb >> 6) << 7);
            } else {
                row = qm * 32 + (lr & 31) + ((lr >> 5) << 6);
                rb  = qm * 32 + (cb & 31) + ((cb >> 5) << 6);
            }
            gll16(A + (size_t)(m0 + row) * K + tile * 64 + ((sc ^ lr8) * 8),
                  &As[buf][rb * 64]);
        }
    };
    auto stageB = [&](int buf, int qn, int tile) {
#pragma unroll
        for (int i = 0; i < 2; i++) {
            int cb  = (i * 8 + w) * 8;
            int lr  = cb + lr8;
            int row = ((lr >> 5) << 6) + qn * 32 + (lr & 31);
            int rb  = ((cb >> 5) << 6) + qn * 32 + (cb & 31);
            gll16(B + (size_t)(n0 + row) * K + tile * 64 + ((sc ^ lr8) * 8),
                  &Bs[buf][rb * 64]);
        }
    };

    const int NT = K >> 6;

    // Prologue: stage tile 0 (order a0,b0,b1,a1), wait a0+b0 landed.
    stageA(0, 0, 0); stageB(0, 0, 0); stageB(0, 1, 0); stageA(0, 1, 0);
    if constexpr (BM == 256) { VM4; } else { VM3; }
    __builtin_amdgcn_s_barrier(); MFEN;

    for (int T = 0; T < NT; ++T) {
        const int buf = T & 1;
        const bool pf = (T + 1 < NT);
        // ---- first half: quadrants of A0/B0 ----
        readB(b0f, buf, 0);
        readA(a0f, buf, 0);
        if (pf) { stageA(buf ^ 1, 0, T + 1); stageB(buf ^ 1, 0, T + 1); }
        MMAQ(a0f, b0f, 0, 0);                                    // P1
        if (pf) { if constexpr (BM == 256) { VM4; } else { VM3; } } else { VM0; }
        __builtin_amdgcn_s_barrier(); MFEN;
        // ---- second half: B1, A1 ----
        readB(b1f, buf, 1);
        if (pf) { stageB(buf ^ 1, 1, T + 1); stageA(buf ^ 1, 1, T + 1); }
        MMAQ(a0f, b1f, 0, 1);                                    // P2
        readA(a1f, buf, 1);
        MMAQ(a1f, b1f, 1, 1);                                    // P3
        MMAQ(a1f, b0f, 1, 0);                                    // P4
        if (pf) {
            if constexpr (BM == 256) { VM4; } else { VM3; }
            __builtin_amdgcn_s_barrier(); MFEN;
        }
    }

    // Epilogue C-write.
#pragma unroll
    for (int qm = 0; qm < 2; qm++)
#pragma unroll
      for (int i = 0; i < MIQ; i++)
#pragma unroll
        for (int qn = 0; qn < 2; qn++)
#pragma unroll
          for (int n = 0; n < 2; n++)
#pragma unroll
            for (int r = 0; r < 4; r++) {
                int row = m0 + wm + qm * (WM / 2) + i * 16 + quad * 4 + r;
                int col = n0 + wn + qn * 32 + n * 16 + l15;
                float val = acc[qm * MIQ + i][qn * 2 + n][r];
                if constexpr (sizeof(TC) == 4) C[(size_t)row * N + col] = val;
                else                           C[(size_t)row * N + col] = f2bf(val);
            }
}

// ---------------------------------------------------------------------------
// Legacy 128x128 GEMM (Tier B QKV: f32 A staging path).
// ---------------------------------------------------------------------------
template <typename TA, typename TC>
__global__ __launch_bounds__(256) void gemm_async(const TA* __restrict__ A,
                                                  const ushort* __restrict__ B,
                                                  TC* __restrict__ C,
                                                  int M, int N, int K)
{
    __shared__ __align__(16) ushort As[128 * 32];
    __shared__ __align__(16) ushort Bs[128 * 32];

    const int t    = threadIdx.x;
    const int lane = t & 63;
    const int w    = t >> 6;
    const int l15  = lane & 15;
    const int quad = lane >> 4;
    const int m0   = blockIdx.y * 128;
    const int n0   = blockIdx.x * 128;
    const int wm   = (w >> 1) * 64;
    const int wn   = (w & 1) * 64;
    const int srow = lane >> 2;
    const int scol = ((lane & 3) ^ ((srow >> 1) & 3)) * 8;
    const int sw   = (l15 >> 1) & 3;

    f32x4 acc[4][4] = {};

    for (int kt = 0; kt < K; kt += 32) {
        __syncthreads();
#pragma unroll
        for (int j = 0; j < 2; j++) {
            const int rb = w * 32 + j * 16;
            if constexpr (sizeof(TA) == 2) {
                gll16((const ushort*)A + (size_t)(m0 + rb + srow) * K + kt + scol,
                      As + rb * 32);
            }
            gll16(B + (size_t)(n0 + rb + srow) * K + kt + scol, Bs + rb * 32);
        }
        if constexpr (sizeof(TA) == 4)
            stage_f32(As, (const float*)A, m0, K, kt, t);
        __syncthreads();

        bf16x8 a[4], b[4];
#pragma unroll
        for (int mi = 0; mi < 4; mi++)
            a[mi] = *(const bf16x8*)(As + (wm + mi * 16 + l15) * 32 + (quad ^ sw) * 8);
#pragma unroll
        for (int ni = 0; ni < 4; ni++)
            b[ni] = *(const bf16x8*)(Bs + (wn + ni * 16 + l15) * 32 + (quad ^ sw) * 8);
#pragma unroll
        for (int mi = 0; mi < 4; mi++)
#pragma unroll
            for (int ni = 0; ni < 4; ni++)
                acc[mi][ni] = __builtin_amdgcn_mfma_f32_16x16x32_bf16(
                    a[mi], b[ni], acc[mi][ni], 0, 0, 0);
    }

#pragma unroll
    for (int mi = 0; mi < 4; mi++)
#pragma unroll
        for (int ni = 0; ni < 4; ni++)
#pragma unroll
            for (int r = 0; r < 4; r++) {
                int row = m0 + wm + mi * 16 + quad * 4 + r;
                int col = n0 + wn + ni * 16 + l15;
                float val = acc[mi][ni][r];
                if constexpr (sizeof(TC) == 4) C[(size_t)row * N + col] = val;
                else                           C[(size_t)row * N + col] = f2bf(val);
            }
}

// ---------------------------------------------------------------------------
// Slow-fallback GEMMs (Tier C), swizzle-consistent.
// ---------------------------------------------------------------------------
__global__ __launch_bounds__(256) void gemm_sync(const float* __restrict__ A,
                                                 const float* __restrict__ B,
                                                 ushort* __restrict__ C,
                                                 int M, int N, int K)
{
    __shared__ __align__(16) ushort As[128 * 32];
    __shared__ __align__(16) ushort Bs[128 * 32];
    const int t = threadIdx.x, lane = t & 63, w = t >> 6;
    const int l15 = lane & 15, quad = lane >> 4;
    const int sw = (l15 >> 1) & 3;
    const int m0 = blockIdx.y * 128, n0 = blockIdx.x * 128;
    const int wm = (w >> 1) * 64, wn = (w & 1) * 64;
    f32x4 acc[4][4] = {};
    for (int kt = 0; kt < K; kt += 32) {
        __syncthreads();
        stage_f32(As, A, m0, K, kt, t);
        stage_f32(Bs, B, n0, K, kt, t);
        __syncthreads();
        bf16x8 a[4], b[4];
#pragma unroll
        for (int mi = 0; mi < 4; mi++)
            a[mi] = *(const bf16x8*)(As + (wm + mi * 16 + l15) * 32 + (quad ^ sw) * 8);
#pragma unroll
        for (int ni = 0; ni < 4; ni++)
            b[ni] = *(const bf16x8*)(Bs + (wn + ni * 16 + l15) * 32 + (quad ^ sw) * 8);
#pragma unroll
        for (int mi = 0; mi < 4; mi++)
#pragma unroll
            for (int ni = 0; ni < 4; ni++)
                acc[mi][ni] = __builtin_amdgcn_mfma_f32_16x16x32_bf16(
                    a[mi], b[ni], acc[mi][ni], 0, 0, 0);
    }
#pragma unroll
    for (int mi = 0; mi < 4; mi++)
#pragma unroll
        for (int ni = 0; ni < 4; ni++)
#pragma unroll
            for (int r = 0; r < 4; r++)
                C[(size_t)(m0 + wm + mi * 16 + quad * 4 + r) * N +
                  n0 + wn + ni * 16 + l15] = f2bf(acc[mi][ni][r]);
}

__global__ __launch_bounds__(256) void gemm_sync_hf(const ushort* __restrict__ A,
                                                    const float* __restrict__ B,
                                                    float* __restrict__ C,
                                                    int M, int N, int K)
{
    __shared__ __align__(16) ushort As[128 * 32];
    __shared__ __align__(16) ushort Bs[128 * 32];
    const int t = threadIdx.x, lane = t & 63, w = t >> 6;
    const int l15 = lane & 15, quad = lane >> 4;
    const int sw = (l15 >> 1) & 3;
    const int m0 = blockIdx.y * 128, n0 = blockIdx.x * 128;
    const int wm = (w >> 1) * 64, wn = (w & 1) * 64;
    f32x4 acc[4][4] = {};
    for (int kt = 0; kt < K; kt += 32) {
        __syncthreads();
#pragma unroll
        for (int i = 0; i < 2; i++) {
            int g = t + i * 256;
            int row = g >> 2, c = g & 3;
            int cl = c ^ ((row >> 1) & 3);
            *(uint4*)(As + row * 32 + cl * 8) =
                *(const uint4*)(A + (size_t)(m0 + row) * K + kt + c * 8);
        }
        stage_f32(Bs, B, n0, K, kt, t);
        __syncthreads();
        bf16x8 a[4], b[4];
#pragma unroll
        for (int mi = 0; mi < 4; mi++)
            a[mi] = *(const bf16x8*)(As + (wm + mi * 16 + l15) * 32 + (quad ^ sw) * 8);
#pragma unroll
        for (int ni = 0; ni < 4; ni++)
            b[ni] = *(const bf16x8*)(Bs + (wn + ni * 16 + l15) * 32 + (quad ^ sw) * 8);
#pragma unroll
        for (int mi = 0; mi < 4; mi++)
#pragma unroll
            for (int ni = 0; ni < 4; ni++)
                acc[mi][ni] = __builtin_amdgcn_mfma_f32_16x16x32_bf16(
                    a[mi], b[ni], acc[mi][ni], 0, 0, 0);
    }
#pragma unroll
    for (int mi = 0; mi < 4; mi++)
#pragma unroll
        for (int ni = 0; ni < 4; ni++)
#pragma unroll
            for (int r = 0; r < 4; r++)
                C[(size_t)(m0 + wm + mi * 16 + quad * 4 + r) * N +
                  n0 + wn + ni * 16 + l15] = acc[mi][ni][r];
}

// ---------------------------------------------------------------------------
// RoPE in-place on rows of stride `stride`, nh heads at column h*256.
// ---------------------------------------------------------------------------
__global__ void rope_kernel(ushort* __restrict__ x, int stride,
                            const float* __restrict__ cosb,
                            const float* __restrict__ sinb, int nh)
{
    int idx  = blockIdx.x * blockDim.x + threadIdx.x;
    int d    = idx & 127;
    int rest = idx >> 7;
    int h    = rest & (nh - 1);
    int s    = rest / nh;
    size_t base = (size_t)s * stride + h * DHEAD;
    float c  = cosb[s * DHEAD + d];
    float sn = sinb[s * DHEAD + d];
    float x1 = bf2f(x[base + d]);
    float x2 = bf2f(x[base + d + 128]);
    x[base + d]       = f2bf(x1 * c - x2 * sn);
    x[base + d + 128] = f2bf(x2 * c + x1 * sn);
}

// ---------------------------------------------------------------------------
// Transpose V rows (stride) -> Vt [KD][S_LEN], 64x64 tiles.
// ---------------------------------------------------------------------------
__global__ __launch_bounds__(256) void vtrans_kernel(const ushort* __restrict__ v,
                                                     int stride,
                                                     ushort* __restrict__ vt)
{
    __shared__ __align__(16) ushort tile[64][72];
    int s0 = blockIdx.x * 64, c0 = blockIdx.y * 64;
    int t  = threadIdx.x;
#pragma unroll
    for (int i = 0; i < 2; i++) {
        int cI = t + i * 256;
        int row = cI >> 3, c8 = cI & 7;
        *(uint4*)&tile[row][c8 * 8] =
            *(const uint4*)(v + (size_t)(s0 + row) * stride + c0 + c8 * 8);
    }
    __syncthreads();
#pragma unroll
    for (int i = 0; i < 2; i++) {
        int cI = t + i * 256;
        int crow = cI >> 3, s8 = cI & 7;
        ushort tmp[8];
#pragma unroll
        for (int j = 0; j < 8; j++) tmp[j] = tile[s8 * 8 + j][crow];
        *(uint4*)(vt + (size_t)(c0 + crow) * S_LEN + s0 + s8 * 8) = *(uint4*)tmp;
    }
}

// ---------------------------------------------------------------------------
// Flash attention, block = 64 q-rows x 1 head, 4 waves (16 rows each).
// ---------------------------------------------------------------------------
template <typename TO>
__global__ __launch_bounds__(256) void attn_kernel(const ushort* __restrict__ qr, int qstride,
                                                   const ushort* __restrict__ kr, int kstride,
                                                   const ushort* __restrict__ vt,
                                                   TO* __restrict__ out)
{
    __shared__ __align__(16) ushort Ks[64 * 256];   // [key][d] 32KB
    __shared__ __align__(16) ushort Vs[256 * 64];   // [d][key] 32KB
    __shared__ __align__(16) ushort Ps[4][16 * 68]; // padded, 8.5KB

    const int t    = threadIdx.x;
    const int lane = t & 63;
    const int w    = t >> 6;
    const int l15  = lane & 15;
    const int quad = lane >> 4;
    const int q0B  = blockIdx.x * 64;
    const int q0   = q0B + w * 16;
    const int h    = blockIdx.y;
    const int kvh  = h >> 1;  // GROUPS = 2

    bf16x8 aQ[8];
    const ushort* qrow = qr + (size_t)(q0 + l15) * qstride + h * DHEAD;
#pragma unroll
    for (int kk = 0; kk < 8; kk++)
        aQ[kk] = *(const bf16x8*)(qrow + kk * 32 + quad * 8);

    f32x4 oacc[16] = {};
    float m_i[4], l_i[4];
#pragma unroll
    for (int r = 0; r < 4; r++) { m_i[r] = -1e30f; l_i[r] = 0.f; }

    int km = q0B - (WINDOW - 1);
    if (km < 0) km = 0;
    km &= ~63;

    for (int kb = km; kb < q0B + 64; kb += 64) {
        __syncthreads();
#pragma unroll
        for (int i = 0; i < 8; i++) {
            int base = i * 256 + w * 64;
            int idx  = base + lane;
            int row = idx >> 5, c = idx & 31;
            int cs = c ^ (row & 7);
            gll16(kr + (size_t)(kb + row) * kstride + kvh * DHEAD + cs * 8,
                  Ks + base * 8);
        }
#pragma unroll
        for (int i = 0; i < 8; i++) {
            int base = i * 256 + w * 64;
            int idx  = base + lane;
            int row = idx >> 3, c = idx & 7;
            int cs = c ^ (row & 7);
            gll16(vt + (size_t)(kvh * DHEAD + row) * S_LEN + kb + cs * 8,
                  Vs + base * 8);
        }
        __syncthreads();

        // ---- QK^T: S[16q][64k] ----
        f32x4 sc[4] = {};
#pragma unroll
        for (int ni = 0; ni < 4; ni++) {
            int row = ni * 16 + l15;
#pragma unroll
            for (int kk = 0; kk < 8; kk++) {
                int cp = (kk * 4 + quad) ^ (row & 7);
                bf16x8 bk = *(const bf16x8*)(Ks + row * 256 + cp * 8);
                sc[ni] = __builtin_amdgcn_mfma_f32_16x16x32_bf16(aQ[kk], bk, sc[ni], 0, 0, 0);
            }
        }

        // ---- softcap + mask + online softmax ----
        const bool interior = (kb + 63 <= q0) && (q0 + 15 - kb < WINDOW);
        float p[4][4];
        float mt[4] = { -1e30f, -1e30f, -1e30f, -1e30f };
        if (interior) {
#pragma unroll
            for (int ni = 0; ni < 4; ni++)
#pragma unroll
                for (int r = 0; r < 4; r++) {
                    float e = __expf(sc[ni][r] * 0.0025f);
                    float x = 50.f * (e - 1.f) * __builtin_amdgcn_rcpf(e + 1.f);
                    p[ni][r] = x;
                    mt[r] = fmaxf(mt[r], x);
                }
        } else {
#pragma unroll
            for (int ni = 0; ni < 4; ni++)
#pragma unroll
                for (int r = 0; r < 4; r++) {
                    int qi = q0 + quad * 4 + r;
                    int ki = kb + ni * 16 + l15;
                    float e = __expf(sc[ni][r] * 0.0025f);
                    float x = 50.f * (e - 1.f) * __builtin_amdgcn_rcpf(e + 1.f);
                    bool ok = (ki <= qi) && (qi - ki < WINDOW);
                    x = ok ? x : MASK_VAL;
                    p[ni][r] = x;
                    mt[r] = fmaxf(mt[r], x);
                }
        }
#pragma unroll
        for (int r = 0; r < 4; r++)
#pragma unroll
            for (int off = 1; off < 16; off <<= 1)
                mt[r] = fmaxf(mt[r], __shfl_xor(mt[r], off));

        float alpha[4], rs[4];
#pragma unroll
        for (int r = 0; r < 4; r++) {
            float mn = fmaxf(m_i[r], mt[r]);
            alpha[r] = __expf(m_i[r] - mn);
            m_i[r] = mn;
            rs[r] = 0.f;
        }
#pragma unroll
        for (int ni = 0; ni < 4; ni++)
#pragma unroll
            for (int r = 0; r < 4; r++) {
                float pe = __expf(p[ni][r] - m_i[r]);
                rs[r] += pe;
                Ps[w][(quad * 4 + r) * 68 + ni * 16 + l15] = f2bf(pe);
            }
#pragma unroll
        for (int r = 0; r < 4; r++) {
#pragma unroll
            for (int off = 1; off < 16; off <<= 1)
                rs[r] += __shfl_xor(rs[r], off);
            l_i[r] = l_i[r] * alpha[r] + rs[r];
        }
#pragma unroll
        for (int nd = 0; nd < 16; nd++)
#pragma unroll
            for (int r = 0; r < 4; r++)
                oacc[nd][r] *= alpha[r];

        __asm__ volatile("s_waitcnt lgkmcnt(0)" ::: "memory");

        // ---- PV ----
        bf16x8 aP[2];
#pragma unroll
        for (int kk = 0; kk < 2; kk++)
            aP[kk] = *(const bf16x8*)(&Ps[w][l15 * 68 + kk * 32 + quad * 8]);
#pragma unroll
        for (int nd = 0; nd < 16; nd++) {
            int row = nd * 16 + l15;
#pragma unroll
            for (int kk = 0; kk < 2; kk++) {
                int cp = (kk * 4 + quad) ^ (row & 7);
                bf16x8 bv = *(const bf16x8*)(Vs + row * 64 + cp * 8);
                oacc[nd] = __builtin_amdgcn_mfma_f32_16x16x32_bf16(aP[kk], bv, oacc[nd], 0, 0, 0);
            }
        }
    }

#pragma unroll
    for (int r = 0; r < 4; r++) {
        float invl = __builtin_amdgcn_rcpf(l_i[r]);
#pragma unroll
        for (int nd = 0; nd < 16; nd++) {
            int qi = q0 + quad * 4 + r;
            int d  = nd * 16 + l15;
            float val = oacc[nd][r] * invl;
            if constexpr (sizeof(TO) == 4) out[(size_t)qi * QD + h * DHEAD + d] = val;
            else                           out[(size_t)qi * QD + h * DHEAD + d] = f2bf(val);
        }
    }
}

// ---------------------------------------------------------------------------
extern "C" void kernel_launch(void* const* d_in, const int* in_sizes, int n_in,
                              void* d_out, int out_size, void* d_ws, size_t ws_size,
                              hipStream_t stream)
{
    const float* hidden = (const float*)d_in[0];
    const float* cosb   = (const float*)d_in[1];
    const float* sinb   = (const float*)d_in[2];
    const float* wq     = (const float*)d_in[3];
    const float* wk     = (const float*)d_in[4];
    const float* wv     = (const float*)d_in[5];
    const float* wo     = (const float*)d_in[6];
    float* outp = (float*)d_out;

    const size_t nH   = (size_t)S_LEN * HDIM;
    const size_t nWQ  = (size_t)QD * HDIM;
    const size_t nWK  = (size_t)KD * HDIM;
    const size_t nWB  = (size_t)QKVD * HDIM;
    const size_t nWO  = (size_t)HDIM * QD;
    const size_t nQKV = (size_t)S_LEN * QKVD;
    const size_t nAT  = (size_t)S_LEN * QD;
    const size_t nVT  = (size_t)S_LEN * KD;

    dim3 blk(256);
    dim3 blk512(512);
    const size_t needA = (nWB + nQKV + nH + nWO) * 2;
    const size_t needB = (nWB + nQKV) * 2;

    if (ws_size >= needA) {
        ushort* wb  = (ushort*)d_ws;
        ushort* qkv = wb + nWB;
        ushort* hb  = qkv + nQKV;
        ushort* ob  = hb + nH;
        ushort* at  = wb;                      // alias (wb dead after QKV GEMM)
        ushort* vtb = wb + nAT;

        cvt5_kernel<<<(N_CVT + 255) / 256, blk, 0, stream>>>(hidden, wq, wk, wv, wo, hb, wb, ob);
        gemm256x256<ushort><<<dim3(QKVD / 256, S_LEN / 256), blk512, 0, stream>>>(
            hb, wb, qkv, S_LEN, QKVD, HDIM);
        rope_kernel<<<(S_LEN * NHEAD * 128) / 256, blk, 0, stream>>>(qkv, QKVD, cosb, sinb, NHEAD);
        rope_kernel<<<(S_LEN * NKVH * 128) / 256, blk, 0, stream>>>(qkv + QD, QKVD, cosb, sinb, NKVH);
        vtrans_kernel<<<dim3(S_LEN / 64, KD / 64), blk, 0, stream>>>(qkv + QD + KD, QKVD, vtb);
        attn_kernel<ushort><<<dim3(S_LEN / 64, NHEAD), blk, 0, stream>>>(
            qkv, QKVD, qkv + QD, QKVD, vtb, at);
        gemm2b<128, float><<<dim3(HDIM / 256, S_LEN / 128), blk512, 0, stream>>>(
            at, ob, outp, S_LEN, HDIM, QD);
    } else if (ws_size >= needB) {
        ushort* wb  = (ushort*)d_ws;
        ushort* qkv = wb + nWB;
        ushort* at  = wb;
        ushort* vtb = wb + nAT;
        ushort* ob  = wb + nAT + nVT;

        cvt_kernel<<<(int)(nWQ / 8 / 256), blk, 0, stream>>>(wq, wb, (int)(nWQ / 8));
        cvt_kernel<<<(int)(nWK / 8 / 256), blk, 0, stream>>>(wk, wb + nWQ, (int)(nWK / 8));
        cvt_kernel<<<(int)(nWK / 8 / 256), blk, 0, stream>>>(wv, wb + nWQ + nWK, (int)(nWK / 8));
        gemm_async<float, ushort><<<dim3(QKVD / 128, S_LEN / 128), blk, 0, stream>>>(
            hidden, wb, qkv, S_LEN, QKVD, HDIM);
        cvt_kernel<<<(int)(nWO / 8 / 256), blk, 0, stream>>>(wo, ob, (int)(nWO / 8));
        rope_kernel<<<(S_LEN * NHEAD * 128) / 256, blk, 0, stream>>>(qkv, QKVD, cosb, sinb, NHEAD);
        rope_kernel<<<(S_LEN * NKVH * 128) / 256, blk, 0, stream>>>(qkv + QD, QKVD, cosb, sinb, NKVH);
        vtrans_kernel<<<dim3(S_LEN / 64, KD / 64), blk, 0, stream>>>(qkv + QD + KD, QKVD, vtb);
        attn_kernel<ushort><<<dim3(S_LEN / 64, NHEAD), blk, 0, stream>>>(
            qkv, QKVD, qkv + QD, QKVD, vtb, at);
        gemm2b<128, float><<<dim3(HDIM / 256, S_LEN / 128), blk512, 0, stream>>>(
            at, ob, outp, S_LEN, HDIM, QD);
    } else {
        ushort* q   = (ushort*)d_ws;
        ushort* k   = q + nAT;
        ushort* v   = k + nVT;
        ushort* vtb = v + nVT;
        ushort* at  = vtb + nVT;

        gemm_sync<<<dim3(QD / 128, S_LEN / 128), blk, 0, stream>>>(hidden, wq, q, S_LEN, QD, HDIM);
        gemm_sync<<<dim3(KD / 128, S_LEN / 128), blk, 0, stream>>>(hidden, wk, k, S_LEN, KD, HDIM);
        gemm_sync<<<dim3(KD / 128, S_LEN / 128), blk, 0, stream>>>(hidden, wv, v, S_LEN, KD, HDIM);
        rope_kernel<<<(S_LEN * NHEAD * 128) / 256, blk, 0, stream>>>(q, QD, cosb, sinb, NHEAD);
        rope_kernel<<<(S_LEN * NKVH * 128) / 256, blk, 0, stream>>>(k, KD, cosb, sinb, NKVH);
        vtrans_kernel<<<dim3(S_LEN / 64, KD / 64), blk, 0, stream>>>(v, KD, vtb);
        attn_kernel<ushort><<<dim3(S_LEN / 64, NHEAD), blk, 0, stream>>>(q, QD, k, KD, vtb, at);
        gemm_sync_hf<<<dim3(HDIM / 128, S_LEN / 128), blk, 0, stream>>>(at, wo, outp, S_LEN, HDIM, QD);
    }
}